// Round 1
// baseline (316.244 us; speedup 1.0000x reference)
//
#include <hip/hip_runtime.h>
#include <math.h>

#define BB 16
#define VV 778
#define OO 8192
#define GG 32
#define KNN 5

// log(2*pi) * 3, rounded to f32 like jnp does
#define THREE_LOG2PI 5.513631199228036f

// ---------------- Kernel 1: precompute (gid, cholesky, active, zero out) ---
__global__ void precompute_kernel(const float* __restrict__ anchor_verts,
                                  const float* __restrict__ contact_gaussians,
                                  const float* __restrict__ init_verts,
                                  const float* __restrict__ init_anchors,
                                  int* __restrict__ gid,
                                  float* __restrict__ chol,
                                  float* __restrict__ active,
                                  float* __restrict__ out) {
    int tid = threadIdx.x;
    __shared__ float ax[GG], ay[GG], az[GG], aa[GG];
    if (tid < GG) {
        float x = init_anchors[tid * 3 + 0];
        float y = init_anchors[tid * 3 + 1];
        float z = init_anchors[tid * 3 + 2];
        ax[tid] = x; ay[tid] = y; az[tid] = z;
        aa[tid] = x * x + y * y + z * z;
    }
    __syncthreads();

    // gid[v] = argmin_g dist(init_verts[v], init_anchors[g]) (first-min)
    for (int v = tid; v < VV; v += blockDim.x) {
        float x = init_verts[v * 3 + 0];
        float y = init_verts[v * 3 + 1];
        float z = init_verts[v * 3 + 2];
        float vv = x * x + y * y + z * z;
        float best = INFINITY;
        int bg = 0;
        for (int g = 0; g < GG; ++g) {
            float d2 = vv + aa[g] - 2.0f * (x * ax[g] + y * ay[g] + z * az[g]);
            d2 = fmaxf(d2, 0.0f);
            if (d2 < best) { best = d2; bg = g; }
        }
        gid[v] = bg;
    }

    // per (b,g): cholesky of 3x3 cov, half_logdet, mean
    for (int t = tid; t < BB * GG; t += blockDim.x) {
        const float* cg = contact_gaussians + (size_t)t * 12;
        const float* av = anchor_verts + (size_t)t * 3;
        float m0 = cg[0] + av[0], m1 = cg[1] + av[1], m2 = cg[2] + av[2];
        float c00 = cg[3];
        float c10 = cg[6], c11 = cg[7];
        float c20 = cg[9], c21 = cg[10], c22 = cg[11];
        float L00 = sqrtf(c00);
        float L10 = c10 / L00;
        float L20 = c20 / L00;
        float L11 = sqrtf(c11 - L10 * L10);
        float L21 = (c21 - L20 * L10) / L11;
        float L22 = sqrtf(c22 - L20 * L20 - L21 * L21);
        float hld = logf(L00) + logf(L11) + logf(L22);
        float* c = chol + (size_t)t * 10;
        c[0] = L00; c[1] = L10; c[2] = L11;
        c[3] = L20; c[4] = L21; c[5] = L22;
        c[6] = hld;
        c[7] = m0; c[8] = m1; c[9] = m2;
    }

    // active[g] = any_{b,c} |cg| > 1e-9
    if (tid < GG) {
        int any = 0;
        for (int b = 0; b < BB && !any; ++b) {
            for (int c = 0; c < 12; ++c) {
                if (fabsf(contact_gaussians[((size_t)b * GG + tid) * 12 + c]) > 1e-9f) {
                    any = 1;
                    break;
                }
            }
        }
        active[tid] = any ? 1.0f : 0.0f;
    }

    if (tid == 0) { out[0] = 0.0f; out[1] = 0.0f; }
}

// ---------------- Kernel 2: per-vertex weight + per-(b,g) seg min/max ------
__global__ void weights_kernel(const float* __restrict__ verts,
                               const int* __restrict__ gid,
                               const float* __restrict__ chol,
                               float* __restrict__ w,
                               float* __restrict__ segmn,
                               float* __restrict__ segmx) {
    int b = blockIdx.x;
    int tid = threadIdx.x;
    __shared__ unsigned int smn[GG], smx[GG];
    if (tid < GG) { smn[tid] = 0x7F800000u; smx[tid] = 0u; }  // +inf / +0
    __syncthreads();

    for (int v = tid; v < VV; v += blockDim.x) {
        int g = gid[v];
        const float* c = chol + ((size_t)b * GG + g) * 10;
        const float* vp = verts + ((size_t)b * VV + v) * 3;
        float d0 = vp[0] - c[7];
        float d1 = vp[1] - c[8];
        float d2 = vp[2] - c[9];
        float y0 = d0 / c[0];
        float y1 = (d1 - c[1] * y0) / c[2];
        float y2 = (d2 - c[3] * y0 - c[4] * y1) / c[5];
        float maha = y0 * y0 + y1 * y1 + y2 * y2;
        float logp = -0.5f * (maha + THREE_LOG2PI) - c[6];
        float wv = expf(logp);
        w[(size_t)b * VV + v] = wv;
        unsigned int u = __float_as_uint(wv);  // wv >= 0 -> uint order == float order
        atomicMin(&smn[g], u);
        atomicMax(&smx[g], u);
    }
    __syncthreads();
    if (tid < GG) {
        segmn[b * GG + tid] = __uint_as_float(smn[tid]);
        segmx[b * GG + tid] = __uint_as_float(smx[tid]);
    }
}

// ---------------- Kernel 3: heavy scans, wave per (b,v) --------------------
__global__ __launch_bounds__(256) void main_scan_kernel(
    const float* __restrict__ verts,
    const float* __restrict__ obj_pts,
    const float* __restrict__ obj_normals,
    const int* __restrict__ gid,
    const float* __restrict__ w,
    const float* __restrict__ segmn,
    const float* __restrict__ segmx,
    const float* __restrict__ active,
    float* __restrict__ out) {
    int wave = threadIdx.x >> 6;
    int lane = threadIdx.x & 63;
    int task = blockIdx.x * 4 + wave;  // B*V == 12448 == 3112*4, always valid
    int b = task / VV;
    int v = task - b * VV;

    const float* vp = verts + ((size_t)b * VV + v) * 3;
    float x = vp[0], y = vp[1], z = vp[2];
    float vv = x * x + y * y + z * z;

    // ---- top-5 smallest d2 over obj_pts[b] ----
    float t[KNN];
#pragma unroll
    for (int k = 0; k < KNN; ++k) t[k] = INFINITY;

    const float* pb = obj_pts + (size_t)b * OO * 3;
    for (int i = lane; i < OO; i += 64) {
        float px = pb[i * 3 + 0];
        float py = pb[i * 3 + 1];
        float pz = pb[i * 3 + 2];
        float pp = px * px + py * py + pz * pz;
        float d2 = vv + pp - 2.0f * (x * px + y * py + z * pz);
        if (d2 < t[KNN - 1]) {
            t[KNN - 1] = d2;
#pragma unroll
            for (int j = KNN - 1; j > 0; --j) {
                if (t[j] < t[j - 1]) { float tmp = t[j]; t[j] = t[j - 1]; t[j - 1] = tmp; }
            }
        }
    }
    // butterfly merge: all lanes converge to the wave-global top-5
#pragma unroll
    for (int off = 1; off < 64; off <<= 1) {
        float o[KNN];
#pragma unroll
        for (int k = 0; k < KNN; ++k) o[k] = __shfl_xor(t[k], off, 64);
#pragma unroll
        for (int k = 0; k < KNN; ++k) {
            float val = o[k];
            if (val < t[KNN - 1]) {
                t[KNN - 1] = val;
#pragma unroll
                for (int j = KNN - 1; j > 0; --j) {
                    if (t[j] < t[j - 1]) { float tmp = t[j]; t[j] = t[j - 1]; t[j - 1] = tmp; }
                }
            }
        }
    }

    // ---- argmin over obj_normals[b,:, :3] ----
    float bd2 = INFINITY;
    int bi = 0x7FFFFFFF;
    const float* nb = obj_normals + (size_t)b * OO * 6;
    for (int i = lane; i < OO; i += 64) {
        float px = nb[i * 6 + 0];
        float py = nb[i * 6 + 1];
        float pz = nb[i * 6 + 2];
        float pp = px * px + py * py + pz * pz;
        float d2 = vv + pp - 2.0f * (x * px + y * py + z * pz);
        if (d2 < bd2) { bd2 = d2; bi = i; }
    }
#pragma unroll
    for (int off = 1; off < 64; off <<= 1) {
        float od = __shfl_xor(bd2, off, 64);
        int oi = __shfl_xor(bi, off, 64);
        if (od < bd2 || (od == bd2 && oi < bi)) { bd2 = od; bi = oi; }
    }

    // ---- per-task contributions ----
    __shared__ float sdm[4], sp[4];
    if (lane == 0) {
        int g = gid[v];
        float wv = w[(size_t)b * VV + v];
        float mn = segmn[b * GG + g];
        float mx = segmx[b * GG + g];
        float wn = (wv - mn) / (mx - mn);
        float eff = (active[g] != 0.0f && wn > 0.01f) ? wn : 0.0f;
        float sk = 0.0f;
#pragma unroll
        for (int k = 0; k < KNN; ++k) sk += sqrtf(fmaxf(t[k], 0.0f));
        sdm[wave] = eff * sk;

        const float* row = nb + (size_t)bi * 6;
        float n0 = row[3], n1 = row[4], n2 = row[5];
        float r0 = row[0] - 0.002f * n0;
        float r1 = row[1] - 0.002f * n1;
        float r2 = row[2] - 0.002f * n2;
        float dp = n0 * (x - r0) + n1 * (y - r1) + n2 * (z - r2);
        sp[wave] = fmaxf(-dp, 0.0f);
    }
    __syncthreads();
    if (threadIdx.x == 0) {
        float a = (sdm[0] + sdm[1] + sdm[2] + sdm[3]) * (1.0f / ((float)BB * VV * KNN));
        float c = (sp[0] + sp[1] + sp[2] + sp[3]) * (1.0f / ((float)BB * VV));
        atomicAdd(&out[0], a);
        atomicAdd(&out[1], c);
    }
}

extern "C" void kernel_launch(void* const* d_in, const int* in_sizes, int n_in,
                              void* d_out, int out_size, void* d_ws, size_t ws_size,
                              hipStream_t stream) {
    const float* verts = (const float*)d_in[0];
    const float* anchor_verts = (const float*)d_in[1];
    const float* obj_pts = (const float*)d_in[2];
    const float* contact_gaussians = (const float*)d_in[3];
    const float* obj_normals = (const float*)d_in[4];
    const float* init_verts = (const float*)d_in[5];
    const float* init_anchors = (const float*)d_in[6];
    float* out = (float*)d_out;

    char* ws = (char*)d_ws;
    int* gid = (int*)ws;                       // 1024 ints (padded)
    float* chol = (float*)(ws + 4096);         // B*G*10 = 5120 floats
    float* active = chol + 5120;               // 32 floats
    float* segmn = active + 32;                // 512 floats
    float* segmx = segmn + 512;                // 512 floats
    float* w = segmx + 512;                    // B*V = 12448 floats

    hipLaunchKernelGGL(precompute_kernel, dim3(1), dim3(256), 0, stream,
                       anchor_verts, contact_gaussians, init_verts, init_anchors,
                       gid, chol, active, out);
    hipLaunchKernelGGL(weights_kernel, dim3(BB), dim3(256), 0, stream,
                       verts, gid, chol, w, segmn, segmx);
    hipLaunchKernelGGL(main_scan_kernel, dim3((BB * VV) / 4), dim3(256), 0, stream,
                       verts, obj_pts, obj_normals, gid, w, segmn, segmx, active, out);
}

// Round 2
// 242.076 us; speedup vs baseline: 1.3064x; 1.3064x over previous
//
#include <hip/hip_runtime.h>
#include <math.h>

#define BB 16
#define VV 778
#define OO 8192
#define GG 32
#define KNN 5
#define VHALF 389          // VV / 2 (exact)
#define TILE 512

// log(2*pi) * 3 in f32
#define THREE_LOG2PI 5.513631199228036f

// branchless-guarded insert of d2 into ascending sorted 5-list
__device__ __forceinline__ void insert5(float (&t)[KNN], float d2) {
    if (d2 < t[KNN - 1]) {
        t[KNN - 1] = d2;
#pragma unroll
        for (int j = KNN - 1; j > 0; --j) {
            float lo = fminf(t[j], t[j - 1]);
            float hi = fmaxf(t[j], t[j - 1]);
            t[j - 1] = lo;
            t[j] = hi;
        }
    }
}

// ---------------- Kernel 1: precompute (gid, cholesky, active, zero out) ---
__global__ void precompute_kernel(const float* __restrict__ anchor_verts,
                                  const float* __restrict__ contact_gaussians,
                                  const float* __restrict__ init_verts,
                                  const float* __restrict__ init_anchors,
                                  int* __restrict__ gid,
                                  float* __restrict__ chol,
                                  float* __restrict__ active,
                                  float* __restrict__ out) {
    int tid = threadIdx.x;
    __shared__ float ax[GG], ay[GG], az[GG], aa[GG];
    if (tid < GG) {
        float x = init_anchors[tid * 3 + 0];
        float y = init_anchors[tid * 3 + 1];
        float z = init_anchors[tid * 3 + 2];
        ax[tid] = x; ay[tid] = y; az[tid] = z;
        aa[tid] = x * x + y * y + z * z;
    }
    __syncthreads();

    for (int v = tid; v < VV; v += blockDim.x) {
        float x = init_verts[v * 3 + 0];
        float y = init_verts[v * 3 + 1];
        float z = init_verts[v * 3 + 2];
        float vv = x * x + y * y + z * z;
        float best = INFINITY;
        int bg = 0;
        for (int g = 0; g < GG; ++g) {
            float d2 = vv + aa[g] - 2.0f * (x * ax[g] + y * ay[g] + z * az[g]);
            d2 = fmaxf(d2, 0.0f);
            if (d2 < best) { best = d2; bg = g; }
        }
        gid[v] = bg;
    }

    for (int t = tid; t < BB * GG; t += blockDim.x) {
        const float* cg = contact_gaussians + (size_t)t * 12;
        const float* av = anchor_verts + (size_t)t * 3;
        float m0 = cg[0] + av[0], m1 = cg[1] + av[1], m2 = cg[2] + av[2];
        float c00 = cg[3];
        float c10 = cg[6], c11 = cg[7];
        float c20 = cg[9], c21 = cg[10], c22 = cg[11];
        float L00 = sqrtf(c00);
        float L10 = c10 / L00;
        float L20 = c20 / L00;
        float L11 = sqrtf(c11 - L10 * L10);
        float L21 = (c21 - L20 * L10) / L11;
        float L22 = sqrtf(c22 - L20 * L20 - L21 * L21);
        float hld = logf(L00) + logf(L11) + logf(L22);
        float* c = chol + (size_t)t * 10;
        c[0] = L00; c[1] = L10; c[2] = L11;
        c[3] = L20; c[4] = L21; c[5] = L22;
        c[6] = hld;
        c[7] = m0; c[8] = m1; c[9] = m2;
    }

    if (tid < GG) {
        int any = 0;
        for (int b = 0; b < BB && !any; ++b) {
            for (int c = 0; c < 12; ++c) {
                if (fabsf(contact_gaussians[((size_t)b * GG + tid) * 12 + c]) > 1e-9f) {
                    any = 1;
                    break;
                }
            }
        }
        active[tid] = any ? 1.0f : 0.0f;
    }

    if (tid == 0) { out[0] = 0.0f; out[1] = 0.0f; }
}

// ---------------- Kernel 2: per-vertex weight + per-(b,g) seg min/max ------
__global__ void weights_kernel(const float* __restrict__ verts,
                               const int* __restrict__ gid,
                               const float* __restrict__ chol,
                               float* __restrict__ w,
                               float* __restrict__ segmn,
                               float* __restrict__ segmx) {
    int b = blockIdx.x;
    int tid = threadIdx.x;
    __shared__ unsigned int smn[GG], smx[GG];
    if (tid < GG) { smn[tid] = 0x7F800000u; smx[tid] = 0u; }
    __syncthreads();

    for (int v = tid; v < VV; v += blockDim.x) {
        int g = gid[v];
        const float* c = chol + ((size_t)b * GG + g) * 10;
        const float* vp = verts + ((size_t)b * VV + v) * 3;
        float d0 = vp[0] - c[7];
        float d1 = vp[1] - c[8];
        float d2 = vp[2] - c[9];
        float y0 = d0 / c[0];
        float y1 = (d1 - c[1] * y0) / c[2];
        float y2 = (d2 - c[3] * y0 - c[4] * y1) / c[5];
        float maha = y0 * y0 + y1 * y1 + y2 * y2;
        float logp = -0.5f * (maha + THREE_LOG2PI) - c[6];
        float wv = expf(logp);
        w[(size_t)b * VV + v] = wv;
        unsigned int u = __float_as_uint(wv);
        atomicMin(&smn[g], u);
        atomicMax(&smx[g], u);
    }
    __syncthreads();
    if (tid < GG) {
        segmn[b * GG + tid] = __uint_as_float(smn[tid]);
        segmx[b * GG + tid] = __uint_as_float(smx[tid]);
    }
}

// ---------------- Kernel 3: partial scans, thread-per-vertex, LDS broadcast
// grid = BB * P * 2 blocks of 256. Block handles one (batch, point-partition,
// vertex-half). Each thread owns up to 2 vertices (slot0: tid, slot1: tid+256,
// slot1 valid iff tid < VHALF-256=133). Points staged to LDS as {x,y,z,|p|^2},
// read back with uniform address -> broadcast, conflict-free.
__global__ __launch_bounds__(256) void scan_partial_kernel(
    const float* __restrict__ verts,
    const float* __restrict__ obj_pts,
    const float* __restrict__ obj_normals,
    float* __restrict__ top5,   // [B][P][VV][5]
    float* __restrict__ nnd,    // [B][P][VV]
    int*   __restrict__ nni,    // [B][P][VV]
    int P, int logP) {
    int bid = blockIdx.x;
    int vc = bid & 1;
    int p = (bid >> 1) & (P - 1);
    int b = bid >> (1 + logP);
    int tid = threadIdx.x;
    int npts = OO >> logP;
    int base = p * npts;

    int v0 = vc * VHALF + tid;
    bool val1 = (256 + tid) < VHALF;
    int v1 = v0 + (val1 ? 256 : 0);

    float x0, y0, z0, vv0, x1, y1, z1, vv1;
    {
        const float* vp = verts + ((size_t)b * VV + v0) * 3;
        x0 = vp[0]; y0 = vp[1]; z0 = vp[2];
        vv0 = x0 * x0 + y0 * y0 + z0 * z0;
        const float* vq = verts + ((size_t)b * VV + v1) * 3;
        x1 = vq[0]; y1 = vq[1]; z1 = vq[2];
        vv1 = x1 * x1 + y1 * y1 + z1 * z1;
    }

    __shared__ float4 tile[TILE];

    // ---------- phase 1: top-5 over obj_pts partition ----------
    float t0[KNN], t1[KNN];
#pragma unroll
    for (int k = 0; k < KNN; ++k) { t0[k] = INFINITY; t1[k] = INFINITY; }

    const float* pb = obj_pts + (size_t)b * OO * 3;
    for (int c0 = 0; c0 < npts; c0 += TILE) {
        int cn = min(TILE, npts - c0);
        for (int j = tid; j < cn; j += 256) {
            const float* q = pb + (size_t)(base + c0 + j) * 3;
            float px = q[0], py = q[1], pz = q[2];
            tile[j] = make_float4(px, py, pz, px * px + py * py + pz * pz);
        }
        __syncthreads();
#pragma unroll 4
        for (int i = 0; i < cn; ++i) {
            float4 q = tile[i];
            float d2a = vv0 + q.w - 2.0f * (x0 * q.x + y0 * q.y + z0 * q.z);
            insert5(t0, d2a);
            float d2b = vv1 + q.w - 2.0f * (x1 * q.x + y1 * q.y + z1 * q.z);
            insert5(t1, d2b);
        }
        __syncthreads();
    }
    {
        float* o = top5 + (((size_t)b * P + p) * VV + v0) * KNN;
#pragma unroll
        for (int k = 0; k < KNN; ++k) o[k] = t0[k];
        if (val1) {
            float* o1 = top5 + (((size_t)b * P + p) * VV + v1) * KNN;
#pragma unroll
            for (int k = 0; k < KNN; ++k) o1[k] = t1[k];
        }
    }

    // ---------- phase 2: argmin over obj_normals[:, :3] partition ----------
    float bd0 = INFINITY, bd1 = INFINITY;
    int bi0 = 0, bi1 = 0;
    const float* nb = obj_normals + (size_t)b * OO * 6;
    for (int c0 = 0; c0 < npts; c0 += TILE) {
        int cn = min(TILE, npts - c0);
        for (int j = tid; j < cn; j += 256) {
            const float* q = nb + (size_t)(base + c0 + j) * 6;
            float px = q[0], py = q[1], pz = q[2];
            tile[j] = make_float4(px, py, pz, px * px + py * py + pz * pz);
        }
        __syncthreads();
#pragma unroll 4
        for (int i = 0; i < cn; ++i) {
            float4 q = tile[i];
            int gidx = base + c0 + i;
            float d2a = vv0 + q.w - 2.0f * (x0 * q.x + y0 * q.y + z0 * q.z);
            if (d2a < bd0) { bd0 = d2a; bi0 = gidx; }
            float d2b = vv1 + q.w - 2.0f * (x1 * q.x + y1 * q.y + z1 * q.z);
            if (d2b < bd1) { bd1 = d2b; bi1 = gidx; }
        }
        __syncthreads();
    }
    {
        size_t o = ((size_t)b * P + p) * VV + v0;
        nnd[o] = bd0;
        nni[o] = bi0;
        if (val1) {
            size_t o1 = ((size_t)b * P + p) * VV + v1;
            nnd[o1] = bd1;
            nni[o1] = bi1;
        }
    }
}

// ---------------- Kernel 4: merge partials + weights + reduce --------------
__global__ __launch_bounds__(256) void finalize_kernel(
    const float* __restrict__ top5,
    const float* __restrict__ nnd,
    const int* __restrict__ nni,
    const float* __restrict__ obj_normals,
    const float* __restrict__ verts,
    const int* __restrict__ gid,
    const float* __restrict__ w,
    const float* __restrict__ segmn,
    const float* __restrict__ segmx,
    const float* __restrict__ active,
    float* __restrict__ out,
    int P) {
    int t = blockIdx.x * 256 + threadIdx.x;
    float cd = 0.0f, cp = 0.0f;
    if (t < BB * VV) {
        int b = t / VV;
        int v = t - b * VV;

        float m[KNN];
#pragma unroll
        for (int k = 0; k < KNN; ++k) m[k] = INFINITY;
        for (int p = 0; p < P; ++p) {
            const float* src = top5 + (((size_t)b * P + p) * VV + v) * KNN;
#pragma unroll
            for (int k = 0; k < KNN; ++k) insert5(m, src[k]);
        }

        float best = INFINITY;
        int bi = 0;
        for (int p = 0; p < P; ++p) {
            size_t o = ((size_t)b * P + p) * VV + v;
            float d = nnd[o];
            if (d < best) { best = d; bi = nni[o]; }
        }

        int g = gid[v];
        float wv = w[(size_t)b * VV + v];
        float mn = segmn[b * GG + g];
        float mx = segmx[b * GG + g];
        float wn = (wv - mn) / (mx - mn);
        float eff = (active[g] != 0.0f && wn > 0.01f) ? wn : 0.0f;
        float sk = 0.0f;
#pragma unroll
        for (int k = 0; k < KNN; ++k) sk += sqrtf(fmaxf(m[k], 0.0f));
        cd = eff * sk;

        const float* vp = verts + ((size_t)b * VV + v) * 3;
        const float* row = obj_normals + ((size_t)b * OO + bi) * 6;
        float n0 = row[3], n1 = row[4], n2 = row[5];
        float r0 = row[0] - 0.002f * n0;
        float r1 = row[1] - 0.002f * n1;
        float r2 = row[2] - 0.002f * n2;
        float dp = n0 * (vp[0] - r0) + n1 * (vp[1] - r1) + n2 * (vp[2] - r2);
        cp = fmaxf(-dp, 0.0f);
    }

    __shared__ float rd[256], rp[256];
    rd[threadIdx.x] = cd;
    rp[threadIdx.x] = cp;
    __syncthreads();
    for (int s = 128; s > 0; s >>= 1) {
        if (threadIdx.x < s) {
            rd[threadIdx.x] += rd[threadIdx.x + s];
            rp[threadIdx.x] += rp[threadIdx.x + s];
        }
        __syncthreads();
    }
    if (threadIdx.x == 0) {
        atomicAdd(&out[0], rd[0] * (1.0f / ((float)BB * VV * KNN)));
        atomicAdd(&out[1], rp[0] * (1.0f / ((float)BB * VV)));
    }
}

extern "C" void kernel_launch(void* const* d_in, const int* in_sizes, int n_in,
                              void* d_out, int out_size, void* d_ws, size_t ws_size,
                              hipStream_t stream) {
    const float* verts = (const float*)d_in[0];
    const float* anchor_verts = (const float*)d_in[1];
    const float* obj_pts = (const float*)d_in[2];
    const float* contact_gaussians = (const float*)d_in[3];
    const float* obj_normals = (const float*)d_in[4];
    const float* init_verts = (const float*)d_in[5];
    const float* init_anchors = (const float*)d_in[6];
    float* out = (float*)d_out;

    char* ws = (char*)d_ws;
    int* gid = (int*)ws;                           // 1024 ints -> 4096 B
    float* chol = (float*)(ws + 4096);             // 5120 floats -> ends 24576
    float* active = (float*)(ws + 24576);          // 32 floats -> 24704
    float* segmn = (float*)(ws + 24704);           // 512 -> 26752
    float* segmx = (float*)(ws + 26752);           // 512 -> 28800
    float* w = (float*)(ws + 28800);               // 12448 -> 78592
    size_t off = 78592;

    // pick largest power-of-two P (partitions of the 8192 points) fitting ws
    int P = 32;
    while (P > 1 && off + (size_t)BB * P * VV * (KNN + 2) * 4 > ws_size) P >>= 1;
    int logP = 0;
    while ((1 << logP) < P) ++logP;

    float* top5 = (float*)(ws + off);
    off += (size_t)BB * P * VV * KNN * 4;
    float* nnd = (float*)(ws + off);
    off += (size_t)BB * P * VV * 4;
    int* nni = (int*)(ws + off);

    hipLaunchKernelGGL(precompute_kernel, dim3(1), dim3(256), 0, stream,
                       anchor_verts, contact_gaussians, init_verts, init_anchors,
                       gid, chol, active, out);
    hipLaunchKernelGGL(weights_kernel, dim3(BB), dim3(256), 0, stream,
                       verts, gid, chol, w, segmn, segmx);
    hipLaunchKernelGGL(scan_partial_kernel, dim3(BB * P * 2), dim3(256), 0, stream,
                       verts, obj_pts, obj_normals, top5, nnd, nni, P, logP);
    hipLaunchKernelGGL(finalize_kernel, dim3((BB * VV + 255) / 256), dim3(256), 0, stream,
                       top5, nnd, nni, obj_normals, verts, gid, w, segmn, segmx,
                       active, out, P);
}

// Round 4
// 189.400 us; speedup vs baseline: 1.6697x; 1.2781x over previous
//
#include <hip/hip_runtime.h>
#include <math.h>

#define BB 16
#define VV 778
#define OO 8192
#define GG 32
#define KNN 5
#define VHALF 389            // VV/2 rounded up handled via val1
#define THREE_LOG2PI 5.513631199228036f

// ---------------- Kernel A: fused duties + partial scans -------------------
// grid = BB * 2 * P blocks of 256. bid = (b << (1+LOGP)) | (p << 1) | vc.
// Each thread owns 2 vertices of its half (tid, tid+256 if < VHALF).
// Points staged to LDS as {x,y,z,|p|^2}; broadcast reads, conflict-free.
// Stores s = |p|^2 - 2 v.p (vv added in finalize; exact for ordering since vv
// is a per-vertex constant).
template <int LOGP>
__global__ __launch_bounds__(256) void scan_fused_kernel(
    const float* __restrict__ verts,
    const float* __restrict__ anchor_verts,
    const float* __restrict__ obj_pts,
    const float* __restrict__ contact_gaussians,
    const float* __restrict__ obj_normals,
    const float* __restrict__ init_verts,
    const float* __restrict__ init_anchors,
    int* __restrict__ gid_ws,
    float* __restrict__ active_ws,
    float* __restrict__ segmn,
    float* __restrict__ segmx,
    float* __restrict__ w_ws,
    float* __restrict__ top5,     // [B][P][VV][5]
    float* __restrict__ nns,      // [B][P][VV]
    int* __restrict__ nni,        // [B][P][VV]
    float* __restrict__ out) {
    constexpr int P = 1 << LOGP;
    constexpr int NPTS = OO >> LOGP;
    constexpr int CH = (NPTS < 512) ? NPTS : 512;   // LDS chunk

    __shared__ float4 tileP[CH];
    __shared__ float4 tileN[CH];
    __shared__ float anc[GG * 4];
    __shared__ float cholb[GG * 10];
    __shared__ unsigned short gidl[VV];
    __shared__ unsigned int smn[GG], smx[GG];

    int tid = threadIdx.x;
    int bid = blockIdx.x;
    int vc = bid & 1;
    int p = (bid >> 1) & (P - 1);
    int b = bid >> (1 + LOGP);

    // ---------------- duty blocks (block-uniform branch) -------------------
    bool wduty = (p == 0 && vc == 0);               // 16 blocks, one per b
    bool aduty = (p == 0 && vc == 1 && b == 0);     // 1 block
    if (wduty || aduty) {
        if (tid < GG) {
            float x = init_anchors[tid * 3 + 0];
            float y = init_anchors[tid * 3 + 1];
            float z = init_anchors[tid * 3 + 2];
            anc[tid * 4 + 0] = x; anc[tid * 4 + 1] = y;
            anc[tid * 4 + 2] = z; anc[tid * 4 + 3] = x * x + y * y + z * z;
            smn[tid] = 0x7F800000u;
            smx[tid] = 0u;
            if (wduty) {
                const float* cg2 = contact_gaussians + ((size_t)b * GG + tid) * 12;
                const float* av = anchor_verts + ((size_t)b * GG + tid) * 3;
                float c00 = cg2[3];
                float c10 = cg2[6], c11 = cg2[7];
                float c20 = cg2[9], c21 = cg2[10], c22 = cg2[11];
                float L00 = sqrtf(c00);
                float L10 = c10 / L00;
                float L20 = c20 / L00;
                float L11 = sqrtf(c11 - L10 * L10);
                float L21 = (c21 - L20 * L10) / L11;
                float L22 = sqrtf(c22 - L20 * L20 - L21 * L21);
                float* c = cholb + tid * 10;
                c[0] = L00; c[1] = L10; c[2] = L11;
                c[3] = L20; c[4] = L21; c[5] = L22;
                c[6] = logf(L00) + logf(L11) + logf(L22);
                c[7] = cg2[0] + av[0];
                c[8] = cg2[1] + av[1];
                c[9] = cg2[2] + av[2];
            }
        }
        __syncthreads();
        for (int v = tid; v < VV; v += 256) {
            float x = init_verts[v * 3 + 0];
            float y = init_verts[v * 3 + 1];
            float z = init_verts[v * 3 + 2];
            float vv = x * x + y * y + z * z;
            float best = INFINITY;
            int bg = 0;
            for (int g = 0; g < GG; ++g) {
                float d2 = vv + anc[g * 4 + 3] -
                           2.0f * (x * anc[g * 4 + 0] + y * anc[g * 4 + 1] + z * anc[g * 4 + 2]);
                d2 = fmaxf(d2, 0.0f);
                if (d2 < best) { best = d2; bg = g; }
            }
            gidl[v] = (unsigned short)bg;
            if (aduty) gid_ws[v] = bg;
        }
        __syncthreads();
        if (wduty) {
            for (int v = tid; v < VV; v += 256) {
                int g = gidl[v];
                const float* c = cholb + g * 10;
                const float* vp = verts + ((size_t)b * VV + v) * 3;
                float d0 = vp[0] - c[7];
                float d1 = vp[1] - c[8];
                float d2 = vp[2] - c[9];
                float y0 = d0 / c[0];
                float y1 = (d1 - c[1] * y0) / c[2];
                float y2 = (d2 - c[3] * y0 - c[4] * y1) / c[5];
                float maha = y0 * y0 + y1 * y1 + y2 * y2;
                float wv = expf(-0.5f * (maha + THREE_LOG2PI) - c[6]);
                w_ws[(size_t)b * VV + v] = wv;
                unsigned int u = __float_as_uint(wv);
                atomicMin(&smn[g], u);
                atomicMax(&smx[g], u);
            }
            __syncthreads();
            if (tid < GG) {
                segmn[b * GG + tid] = __uint_as_float(smn[tid]);
                segmx[b * GG + tid] = __uint_as_float(smx[tid]);
            }
        }
        if (aduty) {
            if (tid < GG) {
                int any = 0;
                for (int bb = 0; bb < BB && !any; ++bb) {
                    for (int c = 0; c < 12; ++c) {
                        if (fabsf(contact_gaussians[((size_t)bb * GG + tid) * 12 + c]) > 1e-9f) {
                            any = 1;
                            break;
                        }
                    }
                }
                active_ws[tid] = any ? 1.0f : 0.0f;
            }
            if (tid == 0) { out[0] = 0.0f; out[1] = 0.0f; }
        }
        __syncthreads();
    }

    // ---------------- partial scans ----------------------------------------
    int v0 = vc * VHALF + tid;
    bool val1 = (256 + tid) < VHALF;
    int v1 = v0 + (val1 ? 256 : 0);

    float x0, y0, z0, x1, y1, z1;
    {
        const float* vp = verts + ((size_t)b * VV + v0) * 3;
        x0 = vp[0]; y0 = vp[1]; z0 = vp[2];
        const float* vq = verts + ((size_t)b * VV + v1) * 3;
        x1 = vq[0]; y1 = vq[1]; z1 = vq[2];
    }

    float t0[KNN], t1[KNN];
#pragma unroll
    for (int k = 0; k < KNN; ++k) { t0[k] = INFINITY; t1[k] = INFINITY; }
    float bs0 = INFINITY, bs1 = INFINITY;
    int bi0 = 0, bi1 = 0;

    const float* pb = obj_pts + ((size_t)b * OO + p * NPTS) * 3;
    const float* nbp = obj_normals + ((size_t)b * OO + p * NPTS) * 6;

    for (int c0 = 0; c0 < NPTS; c0 += CH) {
        for (int j = tid; j < CH; j += 256) {
            const float* q = pb + (size_t)(c0 + j) * 3;
            float a0 = q[0], a1 = q[1], a2 = q[2];
            tileP[j] = make_float4(a0, a1, a2, a0 * a0 + a1 * a1 + a2 * a2);
            const float* r = nbp + (size_t)(c0 + j) * 6;
            float b0 = r[0], b1 = r[1], b2 = r[2];
            tileN[j] = make_float4(b0, b1, b2, b0 * b0 + b1 * b1 + b2 * b2);
        }
        __syncthreads();

#pragma unroll 4
        for (int i = 0; i < CH; ++i) {
            float4 q = tileP[i];
            // s = |p|^2 - 2 v.p
            float s0 = fmaf(-2.0f, fmaf(x0, q.x, fmaf(y0, q.y, z0 * q.z)), q.w);
            float s1 = fmaf(-2.0f, fmaf(x1, q.x, fmaf(y1, q.y, z1 * q.z)), q.w);
            // 9-op branchless sorted insert (descending in-place)
            t0[4] = fminf(t0[4], fmaxf(t0[3], s0));
            t0[3] = fminf(t0[3], fmaxf(t0[2], s0));
            t0[2] = fminf(t0[2], fmaxf(t0[1], s0));
            t0[1] = fminf(t0[1], fmaxf(t0[0], s0));
            t0[0] = fminf(t0[0], s0);
            t1[4] = fminf(t1[4], fmaxf(t1[3], s1));
            t1[3] = fminf(t1[3], fmaxf(t1[2], s1));
            t1[2] = fminf(t1[2], fmaxf(t1[1], s1));
            t1[1] = fminf(t1[1], fmaxf(t1[0], s1));
            t1[0] = fminf(t1[0], s1);

            float4 n = tileN[i];
            float u0 = fmaf(-2.0f, fmaf(x0, n.x, fmaf(y0, n.y, z0 * n.z)), n.w);
            float u1 = fmaf(-2.0f, fmaf(x1, n.x, fmaf(y1, n.y, z1 * n.z)), n.w);
            int gi = c0 + i;
            if (u0 < bs0) { bs0 = u0; bi0 = gi; }
            if (u1 < bs1) { bs1 = u1; bi1 = gi; }
        }
        __syncthreads();
    }

    {
        float* o = top5 + (((size_t)b * P + p) * VV + v0) * KNN;
#pragma unroll
        for (int k = 0; k < KNN; ++k) o[k] = t0[k];
        size_t oo = ((size_t)b * P + p) * VV + v0;
        nns[oo] = bs0;
        nni[oo] = p * NPTS + bi0;
        if (val1) {
            float* o1 = top5 + (((size_t)b * P + p) * VV + v1) * KNN;
#pragma unroll
            for (int k = 0; k < KNN; ++k) o1[k] = t1[k];
            size_t o2 = ((size_t)b * P + p) * VV + v1;
            nns[o2] = bs1;
            nni[o2] = p * NPTS + bi1;
        }
    }
}

// ---------------- Kernel B: merge partials + weights + reduce --------------
__global__ __launch_bounds__(256) void finalize_kernel(
    const float* __restrict__ top5,
    const float* __restrict__ nns,
    const int* __restrict__ nni,
    const float* __restrict__ obj_normals,
    const float* __restrict__ verts,
    const int* __restrict__ gid,
    const float* __restrict__ w,
    const float* __restrict__ segmn,
    const float* __restrict__ segmx,
    const float* __restrict__ active,
    float* __restrict__ out,
    int P) {
    int t = blockIdx.x * 256 + threadIdx.x;
    float cd = 0.0f, cp = 0.0f;
    if (t < BB * VV) {
        int b = t / VV;
        int v = t - b * VV;

        float m[KNN];
#pragma unroll
        for (int k = 0; k < KNN; ++k) m[k] = INFINITY;
        for (int p = 0; p < P; ++p) {
            const float* src = top5 + (((size_t)b * P + p) * VV + v) * KNN;
            for (int k = 0; k < KNN; ++k) {
                float val = src[k];
                if (val >= m[4]) break;    // src ascending -> rest bigger
                m[4] = val;
#pragma unroll
                for (int j = 4; j > 0; --j) {
                    float lo = fminf(m[j], m[j - 1]);
                    float hi = fmaxf(m[j], m[j - 1]);
                    m[j - 1] = lo;
                    m[j] = hi;
                }
            }
        }

        float bests = INFINITY;
        int besti = 0;
        for (int p = 0; p < P; ++p) {
            size_t o = ((size_t)b * P + p) * VV + v;
            float d = nns[o];
            if (d < bests) { bests = d; besti = nni[o]; }
        }

        const float* vp = verts + ((size_t)b * VV + v) * 3;
        float vx = vp[0], vy = vp[1], vz = vp[2];
        float vv = vx * vx + vy * vy + vz * vz;

        int g = gid[v];
        float wv = w[(size_t)b * VV + v];
        float mn = segmn[b * GG + g];
        float mx = segmx[b * GG + g];
        float wn = (wv - mn) / (mx - mn);
        float eff = (active[g] != 0.0f && wn > 0.01f) ? wn : 0.0f;
        float sk = 0.0f;
#pragma unroll
        for (int k = 0; k < KNN; ++k) sk += sqrtf(fmaxf(vv + m[k], 0.0f));
        cd = eff * sk;

        const float* row = obj_normals + ((size_t)b * OO + besti) * 6;
        float n0 = row[3], n1 = row[4], n2 = row[5];
        float r0 = row[0] - 0.002f * n0;
        float r1 = row[1] - 0.002f * n1;
        float r2 = row[2] - 0.002f * n2;
        float dp = n0 * (vx - r0) + n1 * (vy - r1) + n2 * (vz - r2);
        cp = fmaxf(-dp, 0.0f);
    }

    __shared__ float rd[256], rp[256];
    rd[threadIdx.x] = cd;
    rp[threadIdx.x] = cp;
    __syncthreads();
    for (int s = 128; s > 0; s >>= 1) {
        if (threadIdx.x < s) {
            rd[threadIdx.x] += rd[threadIdx.x + s];
            rp[threadIdx.x] += rp[threadIdx.x + s];
        }
        __syncthreads();
    }
    if (threadIdx.x == 0) {
        atomicAdd(&out[0], rd[0] * (1.0f / ((float)BB * VV * KNN)));
        atomicAdd(&out[1], rp[0] * (1.0f / ((float)BB * VV)));
    }
}

extern "C" void kernel_launch(void* const* d_in, const int* in_sizes, int n_in,
                              void* d_out, int out_size, void* d_ws, size_t ws_size,
                              hipStream_t stream) {
    const float* verts = (const float*)d_in[0];
    const float* anchor_verts = (const float*)d_in[1];
    const float* obj_pts = (const float*)d_in[2];
    const float* contact_gaussians = (const float*)d_in[3];
    const float* obj_normals = (const float*)d_in[4];
    const float* init_verts = (const float*)d_in[5];
    const float* init_anchors = (const float*)d_in[6];
    float* out = (float*)d_out;

    char* ws = (char*)d_ws;
    int* gid_ws = (int*)(ws + 0);            // 778 ints        -> 4096
    float* active_ws = (float*)(ws + 4096);  // 32 floats       -> 4224
    float* segmn = (float*)(ws + 4224);      // 512 floats      -> 6272
    float* segmx = (float*)(ws + 6272);      // 512 floats      -> 8320
    float* w_ws = (float*)(ws + 8320);       // 12448 floats    -> 58112
    const size_t base = 58112;

    // largest power-of-two P (point partitions) whose partials fit ws
    int logP = 5;
    while (logP > 0 &&
           base + (size_t)BB * (1 << logP) * VV * (KNN + 2) * 4 > ws_size)
        --logP;
    int P = 1 << logP;

    float* top5 = (float*)(ws + base);
    float* nns = (float*)(ws + base + (size_t)BB * P * VV * KNN * 4);
    int* nni = (int*)(ws + base + (size_t)BB * P * VV * (KNN + 1) * 4);

    dim3 grid(BB * 2 * P), block(256);
    switch (logP) {
        case 5: hipLaunchKernelGGL(scan_fused_kernel<5>, grid, block, 0, stream,
                    verts, anchor_verts, obj_pts, contact_gaussians, obj_normals,
                    init_verts, init_anchors, gid_ws, active_ws, segmn, segmx,
                    w_ws, top5, nns, nni, out); break;
        case 4: hipLaunchKernelGGL(scan_fused_kernel<4>, grid, block, 0, stream,
                    verts, anchor_verts, obj_pts, contact_gaussians, obj_normals,
                    init_verts, init_anchors, gid_ws, active_ws, segmn, segmx,
                    w_ws, top5, nns, nni, out); break;
        case 3: hipLaunchKernelGGL(scan_fused_kernel<3>, grid, block, 0, stream,
                    verts, anchor_verts, obj_pts, contact_gaussians, obj_normals,
                    init_verts, init_anchors, gid_ws, active_ws, segmn, segmx,
                    w_ws, top5, nns, nni, out); break;
        case 2: hipLaunchKernelGGL(scan_fused_kernel<2>, grid, block, 0, stream,
                    verts, anchor_verts, obj_pts, contact_gaussians, obj_normals,
                    init_verts, init_anchors, gid_ws, active_ws, segmn, segmx,
                    w_ws, top5, nns, nni, out); break;
        case 1: hipLaunchKernelGGL(scan_fused_kernel<1>, grid, block, 0, stream,
                    verts, anchor_verts, obj_pts, contact_gaussians, obj_normals,
                    init_verts, init_anchors, gid_ws, active_ws, segmn, segmx,
                    w_ws, top5, nns, nni, out); break;
        default: hipLaunchKernelGGL(scan_fused_kernel<0>, grid, block, 0, stream,
                    verts, anchor_verts, obj_pts, contact_gaussians, obj_normals,
                    init_verts, init_anchors, gid_ws, active_ws, segmn, segmx,
                    w_ws, top5, nns, nni, out); break;
    }
    hipLaunchKernelGGL(finalize_kernel, dim3((BB * VV + 255) / 256), dim3(256),
                       0, stream, top5, nns, nni, obj_normals, verts, gid_ws,
                       w_ws, segmn, segmx, active_ws, out, P);
}

// Round 5
// 160.927 us; speedup vs baseline: 1.9651x; 1.1769x over previous
//
#include <hip/hip_runtime.h>
#include <math.h>

#define BB 16
#define VV 778
#define OO 8192
#define GG 32
#define KNN 5
#define VHALF 389            // ceil(VV/2)
#define THREE_LOG2PI 5.513631199228036f

// ---------------- Kernel A: two block families in one dispatch -------------
// Family 1 (blocks [0, BB*2*P1)):   KNN partial top-5 over obj_pts
// Family 2 (blocks [BB*2*P1, +BB*2*P2)): NN argmin over obj_normals[:,:3]
//                                        + duty blocks (gid/chol/weights/active)
// Layouts: top5 [b][p][k][v], nns/nni [b][p][v]  (coalesced stores & loads).
// s-values stored without |v|^2 (per-vertex constant; added in finalize).
template <int LOGP1, int LOGP2>
__global__ __launch_bounds__(256) void scan_kernel(
    const float* __restrict__ verts,
    const float* __restrict__ anchor_verts,
    const float* __restrict__ obj_pts,
    const float* __restrict__ contact_gaussians,
    const float* __restrict__ obj_normals,
    const float* __restrict__ init_verts,
    const float* __restrict__ init_anchors,
    int* __restrict__ gid_ws,
    float* __restrict__ active_ws,
    float* __restrict__ segmn,
    float* __restrict__ segmx,
    float* __restrict__ w_ws,
    float* __restrict__ top5,     // [B][P1][KNN][VV]
    float* __restrict__ nns,      // [B][P2][VV]
    int* __restrict__ nni,        // [B][P2][VV]
    float* __restrict__ out) {
    constexpr int P1 = 1 << LOGP1;
    constexpr int NPTS1 = OO >> LOGP1;
    constexpr int CH1 = (NPTS1 < 512) ? NPTS1 : 512;
    constexpr int P2 = 1 << LOGP2;
    constexpr int NPTS2 = OO >> LOGP2;
    constexpr int CH2 = (NPTS2 < 512) ? NPTS2 : 512;
    constexpr int CHMAX = (CH1 > CH2) ? CH1 : CH2;

    __shared__ float4 tile[CHMAX];
    __shared__ float anc[GG * 4];
    __shared__ float cholb[GG * 10];
    __shared__ unsigned short gidl[VV];
    __shared__ unsigned int smn[GG], smx[GG];

    int tid = threadIdx.x;
    int bid = blockIdx.x;

    if (bid < BB * 2 * P1) {
        // ================= Family 1: KNN top-5 =============================
        int vc = bid & 1;
        int p = (bid >> 1) & (P1 - 1);
        int b = bid >> (1 + LOGP1);

        int v0 = vc * VHALF + tid;
        bool val1 = (256 + tid) < VHALF;
        int v1 = v0 + (val1 ? 256 : 0);

        float X0, Y0, Z0, X1, Y1, Z1;
        {
            const float* vp = verts + ((size_t)b * VV + v0) * 3;
            X0 = -2.0f * vp[0]; Y0 = -2.0f * vp[1]; Z0 = -2.0f * vp[2];
            const float* vq = verts + ((size_t)b * VV + v1) * 3;
            X1 = -2.0f * vq[0]; Y1 = -2.0f * vq[1]; Z1 = -2.0f * vq[2];
        }

        float t0[KNN], t1[KNN];
#pragma unroll
        for (int k = 0; k < KNN; ++k) { t0[k] = INFINITY; t1[k] = INFINITY; }

        const float* pb = obj_pts + ((size_t)b * OO + p * NPTS1) * 3;
        for (int c0 = 0; c0 < NPTS1; c0 += CH1) {
            for (int j = tid; j < CH1; j += 256) {
                const float* q = pb + (size_t)(c0 + j) * 3;
                float a0 = q[0], a1 = q[1], a2 = q[2];
                tile[j] = make_float4(a0, a1, a2, a0 * a0 + a1 * a1 + a2 * a2);
            }
            __syncthreads();
#pragma unroll 8
            for (int i = 0; i < CH1; ++i) {
                float4 q = tile[i];
                float s0 = fmaf(X0, q.x, fmaf(Y0, q.y, fmaf(Z0, q.z, q.w)));
                float s1 = fmaf(X1, q.x, fmaf(Y1, q.y, fmaf(Z1, q.z, q.w)));
                t0[4] = fminf(t0[4], fmaxf(t0[3], s0));
                t0[3] = fminf(t0[3], fmaxf(t0[2], s0));
                t0[2] = fminf(t0[2], fmaxf(t0[1], s0));
                t0[1] = fminf(t0[1], fmaxf(t0[0], s0));
                t0[0] = fminf(t0[0], s0);
                t1[4] = fminf(t1[4], fmaxf(t1[3], s1));
                t1[3] = fminf(t1[3], fmaxf(t1[2], s1));
                t1[2] = fminf(t1[2], fmaxf(t1[1], s1));
                t1[1] = fminf(t1[1], fmaxf(t1[0], s1));
                t1[0] = fminf(t1[0], s1);
            }
            __syncthreads();
        }
        {
            size_t base = ((size_t)(b * P1 + p) * KNN) * VV;
#pragma unroll
            for (int k = 0; k < KNN; ++k) top5[base + (size_t)k * VV + v0] = t0[k];
            if (val1) {
#pragma unroll
                for (int k = 0; k < KNN; ++k) top5[base + (size_t)k * VV + v1] = t1[k];
            }
        }
        return;
    }

    // ================= Family 2: NN argmin (+ duties) ======================
    {
        int sub = bid - BB * 2 * P1;
        int vc = sub & 1;
        int p = (sub >> 1) & (P2 - 1);
        int b = sub >> (1 + LOGP2);

        bool wduty = (p == 0 && vc == 0);               // 16 blocks, one per b
        bool aduty = (p == 0 && vc == 1 && b == 0);     // 1 block
        if (wduty || aduty) {
            if (tid < GG) {
                float x = init_anchors[tid * 3 + 0];
                float y = init_anchors[tid * 3 + 1];
                float z = init_anchors[tid * 3 + 2];
                anc[tid * 4 + 0] = x; anc[tid * 4 + 1] = y;
                anc[tid * 4 + 2] = z; anc[tid * 4 + 3] = x * x + y * y + z * z;
                smn[tid] = 0x7F800000u;
                smx[tid] = 0u;
                if (wduty) {
                    const float* cg2 = contact_gaussians + ((size_t)b * GG + tid) * 12;
                    const float* av = anchor_verts + ((size_t)b * GG + tid) * 3;
                    float c00 = cg2[3];
                    float c10 = cg2[6], c11 = cg2[7];
                    float c20 = cg2[9], c21 = cg2[10], c22 = cg2[11];
                    float L00 = sqrtf(c00);
                    float L10 = c10 / L00;
                    float L20 = c20 / L00;
                    float L11 = sqrtf(c11 - L10 * L10);
                    float L21 = (c21 - L20 * L10) / L11;
                    float L22 = sqrtf(c22 - L20 * L20 - L21 * L21);
                    float* c = cholb + tid * 10;
                    c[0] = L00; c[1] = L10; c[2] = L11;
                    c[3] = L20; c[4] = L21; c[5] = L22;
                    c[6] = logf(L00) + logf(L11) + logf(L22);
                    c[7] = cg2[0] + av[0];
                    c[8] = cg2[1] + av[1];
                    c[9] = cg2[2] + av[2];
                }
            }
            __syncthreads();
            for (int v = tid; v < VV; v += 256) {
                float x = init_verts[v * 3 + 0];
                float y = init_verts[v * 3 + 1];
                float z = init_verts[v * 3 + 2];
                float vv = x * x + y * y + z * z;
                float best = INFINITY;
                int bg = 0;
                for (int g = 0; g < GG; ++g) {
                    float d2 = vv + anc[g * 4 + 3] -
                               2.0f * (x * anc[g * 4 + 0] + y * anc[g * 4 + 1] + z * anc[g * 4 + 2]);
                    d2 = fmaxf(d2, 0.0f);
                    if (d2 < best) { best = d2; bg = g; }
                }
                gidl[v] = (unsigned short)bg;
                if (aduty) gid_ws[v] = bg;
            }
            __syncthreads();
            if (wduty) {
                for (int v = tid; v < VV; v += 256) {
                    int g = gidl[v];
                    const float* c = cholb + g * 10;
                    const float* vp = verts + ((size_t)b * VV + v) * 3;
                    float d0 = vp[0] - c[7];
                    float d1 = vp[1] - c[8];
                    float d2 = vp[2] - c[9];
                    float y0 = d0 / c[0];
                    float y1 = (d1 - c[1] * y0) / c[2];
                    float y2 = (d2 - c[3] * y0 - c[4] * y1) / c[5];
                    float maha = y0 * y0 + y1 * y1 + y2 * y2;
                    float wv = expf(-0.5f * (maha + THREE_LOG2PI) - c[6]);
                    w_ws[(size_t)b * VV + v] = wv;
                    unsigned int u = __float_as_uint(wv);
                    atomicMin(&smn[g], u);
                    atomicMax(&smx[g], u);
                }
                __syncthreads();
                if (tid < GG) {
                    segmn[b * GG + tid] = __uint_as_float(smn[tid]);
                    segmx[b * GG + tid] = __uint_as_float(smx[tid]);
                }
            }
            if (aduty) {
                if (tid < GG) {
                    int any = 0;
                    for (int bb = 0; bb < BB && !any; ++bb) {
                        for (int c = 0; c < 12; ++c) {
                            if (fabsf(contact_gaussians[((size_t)bb * GG + tid) * 12 + c]) > 1e-9f) {
                                any = 1;
                                break;
                            }
                        }
                    }
                    active_ws[tid] = any ? 1.0f : 0.0f;
                }
                if (tid == 0) { out[0] = 0.0f; out[1] = 0.0f; }
            }
            __syncthreads();
        }

        int v0 = vc * VHALF + tid;
        bool val1 = (256 + tid) < VHALF;
        int v1 = v0 + (val1 ? 256 : 0);

        float X0, Y0, Z0, X1, Y1, Z1;
        {
            const float* vp = verts + ((size_t)b * VV + v0) * 3;
            X0 = -2.0f * vp[0]; Y0 = -2.0f * vp[1]; Z0 = -2.0f * vp[2];
            const float* vq = verts + ((size_t)b * VV + v1) * 3;
            X1 = -2.0f * vq[0]; Y1 = -2.0f * vq[1]; Z1 = -2.0f * vq[2];
        }

        float bs0 = INFINITY, bs1 = INFINITY;
        int bi0 = 0, bi1 = 0;
        const float* nbp = obj_normals + ((size_t)b * OO + p * NPTS2) * 6;
        for (int c0 = 0; c0 < NPTS2; c0 += CH2) {
            for (int j = tid; j < CH2; j += 256) {
                const float* r = nbp + (size_t)(c0 + j) * 6;
                float b0 = r[0], b1 = r[1], b2 = r[2];
                tile[j] = make_float4(b0, b1, b2, b0 * b0 + b1 * b1 + b2 * b2);
            }
            __syncthreads();
#pragma unroll 8
            for (int i = 0; i < CH2; ++i) {
                float4 n = tile[i];
                float u0 = fmaf(X0, n.x, fmaf(Y0, n.y, fmaf(Z0, n.z, n.w)));
                float u1 = fmaf(X1, n.x, fmaf(Y1, n.y, fmaf(Z1, n.z, n.w)));
                int gi = c0 + i;
                if (u0 < bs0) { bs0 = u0; bi0 = gi; }
                if (u1 < bs1) { bs1 = u1; bi1 = gi; }
            }
            __syncthreads();
        }
        {
            size_t o = (size_t)(b * P2 + p) * VV + v0;
            nns[o] = bs0;
            nni[o] = p * NPTS2 + bi0;
            if (val1) {
                size_t o1 = (size_t)(b * P2 + p) * VV + v1;
                nns[o1] = bs1;
                nni[o1] = p * NPTS2 + bi1;
            }
        }
    }
}

// ---------------- Kernel B: merge partials + weights + reduce --------------
template <int LOGP1, int LOGP2>
__global__ __launch_bounds__(256) void finalize_kernel(
    const float* __restrict__ top5,
    const float* __restrict__ nns,
    const int* __restrict__ nni,
    const float* __restrict__ obj_normals,
    const float* __restrict__ verts,
    const int* __restrict__ gid,
    const float* __restrict__ w,
    const float* __restrict__ segmn,
    const float* __restrict__ segmx,
    const float* __restrict__ active,
    float* __restrict__ out) {
    constexpr int P1 = 1 << LOGP1;
    constexpr int P2 = 1 << LOGP2;
    int t = blockIdx.x * 256 + threadIdx.x;
    float cd = 0.0f, cp = 0.0f;
    if (t < BB * VV) {
        int b = t / VV;
        int v = t - b * VV;

        float m[KNN];
#pragma unroll
        for (int k = 0; k < KNN; ++k) m[k] = INFINITY;
        for (int p = 0; p < P1; ++p) {
            size_t base = ((size_t)(b * P1 + p) * KNN) * VV + v;
            float a0 = top5[base];
            float a1 = top5[base + VV];
            float a2 = top5[base + 2 * VV];
            float a3 = top5[base + 3 * VV];
            float a4 = top5[base + 4 * VV];
            // diminishing sorted-insert (a0<=a1<=...<=a4): 25 min/max ops
            m[4] = fminf(m[4], fmaxf(m[3], a0));
            m[3] = fminf(m[3], fmaxf(m[2], a0));
            m[2] = fminf(m[2], fmaxf(m[1], a0));
            m[1] = fminf(m[1], fmaxf(m[0], a0));
            m[0] = fminf(m[0], a0);
            m[4] = fminf(m[4], fmaxf(m[3], a1));
            m[3] = fminf(m[3], fmaxf(m[2], a1));
            m[2] = fminf(m[2], fmaxf(m[1], a1));
            m[1] = fminf(m[1], a1);
            m[4] = fminf(m[4], fmaxf(m[3], a2));
            m[3] = fminf(m[3], fmaxf(m[2], a2));
            m[2] = fminf(m[2], a2);
            m[4] = fminf(m[4], fmaxf(m[3], a3));
            m[3] = fminf(m[3], a3);
            m[4] = fminf(m[4], a4);
        }

        float bests = INFINITY;
        int besti = 0;
        for (int p = 0; p < P2; ++p) {
            size_t o = (size_t)(b * P2 + p) * VV + v;
            float d = nns[o];
            if (d < bests) { bests = d; besti = nni[o]; }
        }

        const float* vp = verts + ((size_t)b * VV + v) * 3;
        float vx = vp[0], vy = vp[1], vz = vp[2];
        float vv = vx * vx + vy * vy + vz * vz;

        int g = gid[v];
        float wv = w[(size_t)b * VV + v];
        float mn = segmn[b * GG + g];
        float mx = segmx[b * GG + g];
        float wn = (wv - mn) / (mx - mn);
        float eff = (active[g] != 0.0f && wn > 0.01f) ? wn : 0.0f;
        float sk = 0.0f;
#pragma unroll
        for (int k = 0; k < KNN; ++k) sk += sqrtf(fmaxf(vv + m[k], 0.0f));
        cd = eff * sk;

        const float* row = obj_normals + ((size_t)b * OO + besti) * 6;
        float n0 = row[3], n1 = row[4], n2 = row[5];
        float r0 = row[0] - 0.002f * n0;
        float r1 = row[1] - 0.002f * n1;
        float r2 = row[2] - 0.002f * n2;
        float dp = n0 * (vx - r0) + n1 * (vy - r1) + n2 * (vz - r2);
        cp = fmaxf(-dp, 0.0f);
    }

    __shared__ float rd[256], rp[256];
    rd[threadIdx.x] = cd;
    rp[threadIdx.x] = cp;
    __syncthreads();
    for (int s = 128; s > 0; s >>= 1) {
        if (threadIdx.x < s) {
            rd[threadIdx.x] += rd[threadIdx.x + s];
            rp[threadIdx.x] += rp[threadIdx.x + s];
        }
        __syncthreads();
    }
    if (threadIdx.x == 0) {
        atomicAdd(&out[0], rd[0] * (1.0f / ((float)BB * VV * KNN)));
        atomicAdd(&out[1], rp[0] * (1.0f / ((float)BB * VV)));
    }
}

template <int LOGP1, int LOGP2>
static void launch_all(const float* verts, const float* anchor_verts,
                       const float* obj_pts, const float* contact_gaussians,
                       const float* obj_normals, const float* init_verts,
                       const float* init_anchors, int* gid_ws, float* active_ws,
                       float* segmn, float* segmx, float* w_ws, float* top5,
                       float* nns, int* nni, float* out, hipStream_t stream) {
    constexpr int P1 = 1 << LOGP1;
    constexpr int P2 = 1 << LOGP2;
    dim3 block(256);
    hipLaunchKernelGGL((scan_kernel<LOGP1, LOGP2>), dim3(BB * 2 * (P1 + P2)), block,
                       0, stream, verts, anchor_verts, obj_pts, contact_gaussians,
                       obj_normals, init_verts, init_anchors, gid_ws, active_ws,
                       segmn, segmx, w_ws, top5, nns, nni, out);
    hipLaunchKernelGGL((finalize_kernel<LOGP1, LOGP2>), dim3((BB * VV + 255) / 256),
                       block, 0, stream, top5, nns, nni, obj_normals, verts,
                       gid_ws, w_ws, segmn, segmx, active_ws, out);
}

extern "C" void kernel_launch(void* const* d_in, const int* in_sizes, int n_in,
                              void* d_out, int out_size, void* d_ws, size_t ws_size,
                              hipStream_t stream) {
    const float* verts = (const float*)d_in[0];
    const float* anchor_verts = (const float*)d_in[1];
    const float* obj_pts = (const float*)d_in[2];
    const float* contact_gaussians = (const float*)d_in[3];
    const float* obj_normals = (const float*)d_in[4];
    const float* init_verts = (const float*)d_in[5];
    const float* init_anchors = (const float*)d_in[6];
    float* out = (float*)d_out;

    char* ws = (char*)d_ws;
    int* gid_ws = (int*)(ws + 0);            // 778 ints        -> 4096
    float* active_ws = (float*)(ws + 4096);  // 32 floats       -> 4224
    float* segmn = (float*)(ws + 4224);      // 512 floats      -> 6272
    float* segmx = (float*)(ws + 6272);      // 512 floats      -> 8320
    float* w_ws = (float*)(ws + 8320);       // 12448 floats    -> 58112
    const size_t base = 58112;

    // largest logP1 (with logP2 = logP1-1) whose partials fit ws
    int logP1 = 5;
    while (logP1 > 0) {
        int P1 = 1 << logP1, P2 = 1 << (logP1 > 0 ? logP1 - 1 : 0);
        if (base + (size_t)BB * VV * 4 * (P1 * KNN + P2 * 2) <= ws_size) break;
        --logP1;
    }
    int P1 = 1 << logP1;
    int logP2 = logP1 > 0 ? logP1 - 1 : 0;
    int P2 = 1 << logP2;

    float* top5 = (float*)(ws + base);
    float* nns = (float*)(ws + base + (size_t)BB * P1 * KNN * VV * 4);
    int* nni = (int*)(ws + base + (size_t)BB * VV * 4 * (P1 * KNN + P2));

#define LAUNCH(L1, L2)                                                         \
    launch_all<L1, L2>(verts, anchor_verts, obj_pts, contact_gaussians,        \
                       obj_normals, init_verts, init_anchors, gid_ws,          \
                       active_ws, segmn, segmx, w_ws, top5, nns, nni, out,     \
                       stream)
    switch (logP1) {
        case 5: LAUNCH(5, 4); break;
        case 4: LAUNCH(4, 3); break;
        case 3: LAUNCH(3, 2); break;
        case 2: LAUNCH(2, 1); break;
        case 1: LAUNCH(1, 0); break;
        default: LAUNCH(0, 0); break;
    }
#undef LAUNCH
}

// Round 6
// 144.133 us; speedup vs baseline: 2.1941x; 1.1165x over previous
//
#include <hip/hip_runtime.h>
#include <math.h>

#define BB 16
#define VV 778
#define OO 8192
#define GG 32
#define KNN 5
#define VHALF 389            // VV/2
#define THREE_LOG2PI 5.513631199228036f

// sorted ascending insert: t[j] = min(t[j], max(t[j-1], s)) == med3(s, t[j-1], t[j])
#define MED3 __builtin_amdgcn_fmed3f

__device__ __forceinline__ void insert5_med3(float (&t)[KNN], float s) {
    t[4] = MED3(s, t[3], t[4]);
    t[3] = MED3(s, t[2], t[3]);
    t[2] = MED3(s, t[1], t[2]);
    t[1] = MED3(s, t[0], t[1]);
    t[0] = fminf(t[0], s);
}

// merge sorted ascending b[5] into sorted ascending m[5]: 15 ops
__device__ __forceinline__ void merge5_med3(float (&m)[KNN], const float (&b)[KNN]) {
    m[4] = MED3(b[0], m[3], m[4]);
    m[3] = MED3(b[0], m[2], m[3]);
    m[2] = MED3(b[0], m[1], m[2]);
    m[1] = MED3(b[0], m[0], m[1]);
    m[0] = fminf(m[0], b[0]);
    m[4] = MED3(b[1], m[3], m[4]);
    m[3] = MED3(b[1], m[2], m[3]);
    m[2] = MED3(b[1], m[1], m[2]);
    m[1] = fminf(m[1], b[1]);
    m[4] = MED3(b[2], m[3], m[4]);
    m[3] = MED3(b[2], m[2], m[3]);
    m[2] = fminf(m[2], b[2]);
    m[4] = MED3(b[3], m[3], m[4]);
    m[3] = fminf(m[3], b[3]);
    m[4] = fminf(m[4], b[4]);
}

// ---------------- Kernel A: two block families in one dispatch -------------
template <int LOGP1, int LOGP2>
__global__ __launch_bounds__(256) void scan_kernel(
    const float* __restrict__ verts,
    const float* __restrict__ anchor_verts,
    const float* __restrict__ obj_pts,
    const float* __restrict__ contact_gaussians,
    const float* __restrict__ obj_normals,
    const float* __restrict__ init_verts,
    const float* __restrict__ init_anchors,
    int* __restrict__ gid_ws,
    float* __restrict__ active_ws,
    float* __restrict__ segmn,
    float* __restrict__ segmx,
    float* __restrict__ w_ws,
    float* __restrict__ top5,     // [B][P1][KNN][VV]
    float* __restrict__ nns,      // [B][P2][VV]
    int* __restrict__ nni,        // [B][P2][VV]
    float* __restrict__ out) {
    constexpr int P1 = 1 << LOGP1;
    constexpr int NPTS1 = OO >> LOGP1;
    constexpr int CH1 = (NPTS1 < 512) ? NPTS1 : 512;
    constexpr int P2 = 1 << LOGP2;
    constexpr int NPTS2 = OO >> LOGP2;
    constexpr int CH2 = (NPTS2 < 512) ? NPTS2 : 512;
    constexpr int CHMAX = (CH1 > CH2) ? CH1 : CH2;

    __shared__ float4 tile[CHMAX];
    __shared__ float anc[GG * 4];
    __shared__ float cholb[GG * 10];
    __shared__ unsigned short gidl[VV];
    __shared__ unsigned int smn[GG], smx[GG];

    int tid = threadIdx.x;
    int bid = blockIdx.x;

    if (bid < BB * 2 * P1) {
        // ================= Family 1: KNN top-5 =============================
        int vc = bid & 1;
        int p = (bid >> 1) & (P1 - 1);
        int b = bid >> (1 + LOGP1);

        int v0 = vc * VHALF + tid;
        bool val1 = (256 + tid) < VHALF;
        int v1 = v0 + (val1 ? 256 : 0);

        float X0, Y0, Z0, X1, Y1, Z1;
        {
            const float* vp = verts + ((size_t)b * VV + v0) * 3;
            X0 = -2.0f * vp[0]; Y0 = -2.0f * vp[1]; Z0 = -2.0f * vp[2];
            const float* vq = verts + ((size_t)b * VV + v1) * 3;
            X1 = -2.0f * vq[0]; Y1 = -2.0f * vq[1]; Z1 = -2.0f * vq[2];
        }

        float t0[KNN], t1[KNN];
#pragma unroll
        for (int k = 0; k < KNN; ++k) { t0[k] = INFINITY; t1[k] = INFINITY; }

        const float* pb = obj_pts + ((size_t)b * OO + p * NPTS1) * 3;
        for (int c0 = 0; c0 < NPTS1; c0 += CH1) {
            for (int j = tid; j < CH1; j += 256) {
                const float* q = pb + (size_t)(c0 + j) * 3;
                float a0 = q[0], a1 = q[1], a2 = q[2];
                tile[j] = make_float4(a0, a1, a2, a0 * a0 + a1 * a1 + a2 * a2);
            }
            __syncthreads();
#pragma unroll 8
            for (int i = 0; i < CH1; ++i) {
                float4 q = tile[i];
                float s0 = fmaf(X0, q.x, fmaf(Y0, q.y, fmaf(Z0, q.z, q.w)));
                float s1 = fmaf(X1, q.x, fmaf(Y1, q.y, fmaf(Z1, q.z, q.w)));
                insert5_med3(t0, s0);
                insert5_med3(t1, s1);
            }
            __syncthreads();
        }
        {
            size_t base = ((size_t)(b * P1 + p) * KNN) * VV;
#pragma unroll
            for (int k = 0; k < KNN; ++k) top5[base + (size_t)k * VV + v0] = t0[k];
            if (val1) {
#pragma unroll
                for (int k = 0; k < KNN; ++k) top5[base + (size_t)k * VV + v1] = t1[k];
            }
        }
        return;
    }

    // ================= Family 2: NN argmin (+ duties) ======================
    {
        int sub = bid - BB * 2 * P1;
        int vc = sub & 1;
        int p = (sub >> 1) & (P2 - 1);
        int b = sub >> (1 + LOGP2);

        bool wduty = (p == 0 && vc == 0);               // 16 blocks, one per b
        bool aduty = (p == 0 && vc == 1 && b == 0);     // 1 block
        if (wduty || aduty) {
            if (tid < GG) {
                float x = init_anchors[tid * 3 + 0];
                float y = init_anchors[tid * 3 + 1];
                float z = init_anchors[tid * 3 + 2];
                anc[tid * 4 + 0] = x; anc[tid * 4 + 1] = y;
                anc[tid * 4 + 2] = z; anc[tid * 4 + 3] = x * x + y * y + z * z;
                smn[tid] = 0x7F800000u;
                smx[tid] = 0u;
                if (wduty) {
                    const float* cg2 = contact_gaussians + ((size_t)b * GG + tid) * 12;
                    const float* av = anchor_verts + ((size_t)b * GG + tid) * 3;
                    float c00 = cg2[3];
                    float c10 = cg2[6], c11 = cg2[7];
                    float c20 = cg2[9], c21 = cg2[10], c22 = cg2[11];
                    float L00 = sqrtf(c00);
                    float L10 = c10 / L00;
                    float L20 = c20 / L00;
                    float L11 = sqrtf(c11 - L10 * L10);
                    float L21 = (c21 - L20 * L10) / L11;
                    float L22 = sqrtf(c22 - L20 * L20 - L21 * L21);
                    float* c = cholb + tid * 10;
                    c[0] = L00; c[1] = L10; c[2] = L11;
                    c[3] = L20; c[4] = L21; c[5] = L22;
                    c[6] = logf(L00) + logf(L11) + logf(L22);
                    c[7] = cg2[0] + av[0];
                    c[8] = cg2[1] + av[1];
                    c[9] = cg2[2] + av[2];
                }
            }
            __syncthreads();
            for (int v = tid; v < VV; v += 256) {
                float x = init_verts[v * 3 + 0];
                float y = init_verts[v * 3 + 1];
                float z = init_verts[v * 3 + 2];
                float vv = x * x + y * y + z * z;
                float best = INFINITY;
                int bg = 0;
                for (int g = 0; g < GG; ++g) {
                    float d2 = vv + anc[g * 4 + 3] -
                               2.0f * (x * anc[g * 4 + 0] + y * anc[g * 4 + 1] + z * anc[g * 4 + 2]);
                    d2 = fmaxf(d2, 0.0f);
                    if (d2 < best) { best = d2; bg = g; }
                }
                gidl[v] = (unsigned short)bg;
                if (aduty) gid_ws[v] = bg;
            }
            __syncthreads();
            if (wduty) {
                for (int v = tid; v < VV; v += 256) {
                    int g = gidl[v];
                    const float* c = cholb + g * 10;
                    const float* vp = verts + ((size_t)b * VV + v) * 3;
                    float d0 = vp[0] - c[7];
                    float d1 = vp[1] - c[8];
                    float d2 = vp[2] - c[9];
                    float y0 = d0 / c[0];
                    float y1 = (d1 - c[1] * y0) / c[2];
                    float y2 = (d2 - c[3] * y0 - c[4] * y1) / c[5];
                    float maha = y0 * y0 + y1 * y1 + y2 * y2;
                    float wv = expf(-0.5f * (maha + THREE_LOG2PI) - c[6]);
                    w_ws[(size_t)b * VV + v] = wv;
                    unsigned int u = __float_as_uint(wv);
                    atomicMin(&smn[g], u);
                    atomicMax(&smx[g], u);
                }
                __syncthreads();
                if (tid < GG) {
                    segmn[b * GG + tid] = __uint_as_float(smn[tid]);
                    segmx[b * GG + tid] = __uint_as_float(smx[tid]);
                }
            }
            if (aduty) {
                if (tid < GG) {
                    int any = 0;
                    for (int bb = 0; bb < BB && !any; ++bb) {
                        for (int c = 0; c < 12; ++c) {
                            if (fabsf(contact_gaussians[((size_t)bb * GG + tid) * 12 + c]) > 1e-9f) {
                                any = 1;
                                break;
                            }
                        }
                    }
                    active_ws[tid] = any ? 1.0f : 0.0f;
                }
                if (tid == 0) { out[0] = 0.0f; out[1] = 0.0f; }
            }
            __syncthreads();
        }

        int v0 = vc * VHALF + tid;
        bool val1 = (256 + tid) < VHALF;
        int v1 = v0 + (val1 ? 256 : 0);

        float X0, Y0, Z0, X1, Y1, Z1;
        {
            const float* vp = verts + ((size_t)b * VV + v0) * 3;
            X0 = -2.0f * vp[0]; Y0 = -2.0f * vp[1]; Z0 = -2.0f * vp[2];
            const float* vq = verts + ((size_t)b * VV + v1) * 3;
            X1 = -2.0f * vq[0]; Y1 = -2.0f * vq[1]; Z1 = -2.0f * vq[2];
        }

        float bs0 = INFINITY, bs1 = INFINITY;
        int bi0 = 0, bi1 = 0;
        const float* nbp = obj_normals + ((size_t)b * OO + p * NPTS2) * 6;
        for (int c0 = 0; c0 < NPTS2; c0 += CH2) {
            for (int j = tid; j < CH2; j += 256) {
                const float* r = nbp + (size_t)(c0 + j) * 6;
                float b0 = r[0], b1 = r[1], b2 = r[2];
                tile[j] = make_float4(b0, b1, b2, b0 * b0 + b1 * b1 + b2 * b2);
            }
            __syncthreads();
#pragma unroll 8
            for (int i = 0; i < CH2; ++i) {
                float4 n = tile[i];
                float u0 = fmaf(X0, n.x, fmaf(Y0, n.y, fmaf(Z0, n.z, n.w)));
                float u1 = fmaf(X1, n.x, fmaf(Y1, n.y, fmaf(Z1, n.z, n.w)));
                int gi = c0 + i;
                if (u0 < bs0) { bs0 = u0; bi0 = gi; }
                if (u1 < bs1) { bs1 = u1; bi1 = gi; }
            }
            __syncthreads();
        }
        {
            size_t o = (size_t)(b * P2 + p) * VV + v0;
            nns[o] = bs0;
            nni[o] = p * NPTS2 + bi0;
            if (val1) {
                size_t o1 = (size_t)(b * P2 + p) * VV + v1;
                nns[o1] = bs1;
                nni[o1] = p * NPTS2 + bi1;
            }
        }
    }
}

// ---------------- Kernel B: parallel tree merge + weights + reduce ---------
// grid = BB * 13 blocks of 256. Block handles 64 vertices of one batch.
// tid = pi*64 + vi: pi in [0,4) selects a partition group (wave-uniform),
// vi in [0,64) selects the vertex (lane -> coalesced loads, conflict-free LDS).
template <int LOGP1, int LOGP2>
__global__ __launch_bounds__(256) void finalize_kernel(
    const float* __restrict__ top5,
    const float* __restrict__ nns,
    const int* __restrict__ nni,
    const float* __restrict__ obj_normals,
    const float* __restrict__ verts,
    const int* __restrict__ gid,
    const float* __restrict__ w,
    const float* __restrict__ segmn,
    const float* __restrict__ segmx,
    const float* __restrict__ active,
    float* __restrict__ out) {
    constexpr int P1 = 1 << LOGP1;
    constexpr int P2 = 1 << LOGP2;
    constexpr int NM1 = (P1 + 3) / 4;   // partitions per thread (family 1)
    constexpr int NM2 = (P2 + 3) / 4;   // partitions per thread (family 2)
    constexpr int NCH = (VV + 63) / 64; // 13 vertex chunks

    __shared__ float mt[4][KNN][64];
    __shared__ float sb[4][64];
    __shared__ int ib[4][64];
    __shared__ float rd[256], rp[256];

    int tid = threadIdx.x;
    int pi = tid >> 6;
    int vi = tid & 63;
    int b = blockIdx.x / NCH;
    int chunk = blockIdx.x - b * NCH;
    int v = chunk * 64 + vi;
    bool valid = v < VV;

    // ---- merge my NM1 top-5 partitions ----
    float m[KNN];
#pragma unroll
    for (int k = 0; k < KNN; ++k) m[k] = INFINITY;
    if (valid) {
#pragma unroll
        for (int r = 0; r < NM1; ++r) {
            int p = pi * NM1 + r;
            if (p < P1) {
                size_t base = ((size_t)(b * P1 + p) * KNN) * VV + v;
                float t[KNN];
#pragma unroll
                for (int k = 0; k < KNN; ++k) t[k] = top5[base + (size_t)k * VV];
                merge5_med3(m, t);
            }
        }
    }

    // ---- merge my NM2 argmin partitions ----
    float bs = INFINITY;
    int bi = 0x7FFFFFFF;
    if (valid) {
#pragma unroll
        for (int r = 0; r < NM2; ++r) {
            int p = pi * NM2 + r;
            if (p < P2) {
                size_t o = (size_t)(b * P2 + p) * VV + v;
                float s = nns[o];
                int i = nni[o];
                if (s < bs || (s == bs && i < bi)) { bs = s; bi = i; }
            }
        }
    }

#pragma unroll
    for (int k = 0; k < KNN; ++k) mt[pi][k][vi] = m[k];
    sb[pi][vi] = bs;
    ib[pi][vi] = bi;
    __syncthreads();

    if (pi < 2) {
        float t[KNN];
#pragma unroll
        for (int k = 0; k < KNN; ++k) t[k] = mt[pi + 2][k][vi];
        merge5_med3(m, t);
#pragma unroll
        for (int k = 0; k < KNN; ++k) mt[pi][k][vi] = m[k];
        float s = sb[pi + 2][vi];
        int i = ib[pi + 2][vi];
        if (s < bs || (s == bs && i < bi)) { bs = s; bi = i; }
        sb[pi][vi] = bs;
        ib[pi][vi] = bi;
    }
    __syncthreads();

    float cd = 0.0f, cp = 0.0f;
    if (pi == 0 && valid) {
        float t[KNN];
#pragma unroll
        for (int k = 0; k < KNN; ++k) t[k] = mt[1][k][vi];
        merge5_med3(m, t);
        float s = sb[1][vi];
        int i = ib[1][vi];
        if (s < bs || (s == bs && i < bi)) { bs = s; bi = i; }

        const float* vp = verts + ((size_t)b * VV + v) * 3;
        float vx = vp[0], vy = vp[1], vz = vp[2];
        float vv = vx * vx + vy * vy + vz * vz;

        int g = gid[v];
        float wv = w[(size_t)b * VV + v];
        float mn = segmn[b * GG + g];
        float mx = segmx[b * GG + g];
        float wn = (wv - mn) / (mx - mn);
        float eff = (active[g] != 0.0f && wn > 0.01f) ? wn : 0.0f;
        float sk = 0.0f;
#pragma unroll
        for (int k = 0; k < KNN; ++k) sk += sqrtf(fmaxf(vv + m[k], 0.0f));
        cd = eff * sk;

        const float* row = obj_normals + ((size_t)b * OO + bi) * 6;
        float n0 = row[3], n1 = row[4], n2 = row[5];
        float r0 = row[0] - 0.002f * n0;
        float r1 = row[1] - 0.002f * n1;
        float r2 = row[2] - 0.002f * n2;
        float dp = n0 * (vx - r0) + n1 * (vy - r1) + n2 * (vz - r2);
        cp = fmaxf(-dp, 0.0f);
    }

    rd[tid] = cd;
    rp[tid] = cp;
    __syncthreads();
    for (int s = 128; s > 0; s >>= 1) {
        if (tid < s) {
            rd[tid] += rd[tid + s];
            rp[tid] += rp[tid + s];
        }
        __syncthreads();
    }
    if (tid == 0) {
        atomicAdd(&out[0], rd[0] * (1.0f / ((float)BB * VV * KNN)));
        atomicAdd(&out[1], rp[0] * (1.0f / ((float)BB * VV)));
    }
}

template <int LOGP1, int LOGP2>
static void launch_all(const float* verts, const float* anchor_verts,
                       const float* obj_pts, const float* contact_gaussians,
                       const float* obj_normals, const float* init_verts,
                       const float* init_anchors, int* gid_ws, float* active_ws,
                       float* segmn, float* segmx, float* w_ws, float* top5,
                       float* nns, int* nni, float* out, hipStream_t stream) {
    constexpr int P1 = 1 << LOGP1;
    constexpr int P2 = 1 << LOGP2;
    constexpr int NCH = (VV + 63) / 64;
    dim3 block(256);
    hipLaunchKernelGGL((scan_kernel<LOGP1, LOGP2>), dim3(BB * 2 * (P1 + P2)), block,
                       0, stream, verts, anchor_verts, obj_pts, contact_gaussians,
                       obj_normals, init_verts, init_anchors, gid_ws, active_ws,
                       segmn, segmx, w_ws, top5, nns, nni, out);
    hipLaunchKernelGGL((finalize_kernel<LOGP1, LOGP2>), dim3(BB * NCH),
                       block, 0, stream, top5, nns, nni, obj_normals, verts,
                       gid_ws, w_ws, segmn, segmx, active_ws, out);
}

extern "C" void kernel_launch(void* const* d_in, const int* in_sizes, int n_in,
                              void* d_out, int out_size, void* d_ws, size_t ws_size,
                              hipStream_t stream) {
    const float* verts = (const float*)d_in[0];
    const float* anchor_verts = (const float*)d_in[1];
    const float* obj_pts = (const float*)d_in[2];
    const float* contact_gaussians = (const float*)d_in[3];
    const float* obj_normals = (const float*)d_in[4];
    const float* init_verts = (const float*)d_in[5];
    const float* init_anchors = (const float*)d_in[6];
    float* out = (float*)d_out;

    char* ws = (char*)d_ws;
    int* gid_ws = (int*)(ws + 0);            // 778 ints        -> 4096
    float* active_ws = (float*)(ws + 4096);  // 32 floats       -> 4224
    float* segmn = (float*)(ws + 4224);      // 512 floats      -> 6272
    float* segmx = (float*)(ws + 6272);      // 512 floats      -> 8320
    float* w_ws = (float*)(ws + 8320);       // 12448 floats    -> 58112
    const size_t base = 58112;

    // largest logP1 (with logP2 = logP1-1) whose partials fit ws
    int logP1 = 5;
    while (logP1 > 0) {
        int P1 = 1 << logP1, P2 = 1 << (logP1 > 0 ? logP1 - 1 : 0);
        if (base + (size_t)BB * VV * 4 * (P1 * KNN + P2 * 2) <= ws_size) break;
        --logP1;
    }
    int P1 = 1 << logP1;
    int logP2 = logP1 > 0 ? logP1 - 1 : 0;
    int P2 = 1 << logP2;

    float* top5 = (float*)(ws + base);
    float* nns = (float*)(ws + base + (size_t)BB * P1 * KNN * VV * 4);
    int* nni = (int*)(ws + base + (size_t)BB * VV * 4 * (P1 * KNN + P2));

#define LAUNCH(L1, L2)                                                         \
    launch_all<L1, L2>(verts, anchor_verts, obj_pts, contact_gaussians,        \
                       obj_normals, init_verts, init_anchors, gid_ws,          \
                       active_ws, segmn, segmx, w_ws, top5, nns, nni, out,     \
                       stream)
    switch (logP1) {
        case 5: LAUNCH(5, 4); break;
        case 4: LAUNCH(4, 3); break;
        case 3: LAUNCH(3, 2); break;
        case 2: LAUNCH(2, 1); break;
        case 1: LAUNCH(1, 0); break;
        default: LAUNCH(0, 0); break;
    }
#undef LAUNCH
}

// Round 7
// 140.361 us; speedup vs baseline: 2.2531x; 1.0269x over previous
//
#include <hip/hip_runtime.h>
#include <math.h>

#define BB 16
#define VV 778
#define OO 8192
#define GG 32
#define KNN 5
#define THREE_LOG2PI 5.513631199228036f

// sorted ascending insert: t[j] = min(t[j], max(t[j-1], s)) == med3(s, t[j-1], t[j])
#define MED3 __builtin_amdgcn_fmed3f

__device__ __forceinline__ void insert5_med3(float (&t)[KNN], float s) {
    t[4] = MED3(s, t[3], t[4]);
    t[3] = MED3(s, t[2], t[3]);
    t[2] = MED3(s, t[1], t[2]);
    t[1] = MED3(s, t[0], t[1]);
    t[0] = fminf(t[0], s);
}

// merge sorted ascending b[5] into sorted ascending m[5]: 15 ops
__device__ __forceinline__ void merge5_med3(float (&m)[KNN], const float (&b)[KNN]) {
    m[4] = MED3(b[0], m[3], m[4]);
    m[3] = MED3(b[0], m[2], m[3]);
    m[2] = MED3(b[0], m[1], m[2]);
    m[1] = MED3(b[0], m[0], m[1]);
    m[0] = fminf(m[0], b[0]);
    m[4] = MED3(b[1], m[3], m[4]);
    m[3] = MED3(b[1], m[2], m[3]);
    m[2] = MED3(b[1], m[1], m[2]);
    m[1] = fminf(m[1], b[1]);
    m[4] = MED3(b[2], m[3], m[4]);
    m[3] = MED3(b[2], m[2], m[3]);
    m[2] = fminf(m[2], b[2]);
    m[4] = MED3(b[3], m[3], m[4]);
    m[3] = fminf(m[3], b[3]);
    m[4] = fminf(m[4], b[4]);
}

// monotone float->uint mapping (works for negatives): a<b  <=>  key(a)<key(b)
__device__ __forceinline__ unsigned int fkey(float s) {
    unsigned int u = __float_as_uint(s);
    unsigned int m = (u & 0x80000000u) ? 0xFFFFFFFFu : 0x80000000u;
    return u ^ m;
}

// ---------------- Kernel A: two block families, S=4 vertex slots -----------
// Family 1 (blocks [0, BB*P1)):      partial top-5 over obj_pts -> top5 ws
// Family 2 (blocks [BB*P1,+BB*P2)):  argmin over obj_normals[:,:3] via packed
//                                    u64 atomicMin; + duty blocks.
// Thread owns 4 vertices: tid+{0,256,512,768} (slot3 valid iff tid<10).
template <int LOGP1, int LOGP2>
__global__ __launch_bounds__(256) void scan_kernel(
    const float* __restrict__ verts,
    const float* __restrict__ anchor_verts,
    const float* __restrict__ obj_pts,
    const float* __restrict__ contact_gaussians,
    const float* __restrict__ obj_normals,
    const float* __restrict__ init_verts,
    const float* __restrict__ init_anchors,
    int* __restrict__ gid_ws,
    float* __restrict__ active_ws,
    float* __restrict__ segmn,
    float* __restrict__ segmx,
    float* __restrict__ w_ws,
    float* __restrict__ top5,                 // [B][P1][KNN][VV]
    unsigned long long* __restrict__ amin,    // [B][VV] packed (key<<32)|idx
    float* __restrict__ out) {
    constexpr int P1 = 1 << LOGP1;
    constexpr int NPTS1 = OO >> LOGP1;
    constexpr int CH1 = (NPTS1 < 512) ? NPTS1 : 512;
    constexpr int P2 = 1 << LOGP2;
    constexpr int NPTS2 = OO >> LOGP2;
    constexpr int CH2 = (NPTS2 < 512) ? NPTS2 : 512;
    constexpr int CHMAX = (CH1 > CH2) ? CH1 : CH2;

    __shared__ float4 tile[CHMAX];
    __shared__ float anc[GG * 4];
    __shared__ float cholb[GG * 10];
    __shared__ unsigned short gidl[VV];
    __shared__ unsigned int smn[GG], smx[GG];

    int tid = threadIdx.x;
    int bid = blockIdx.x;

    if (bid < BB * P1) {
        // ================= Family 1: KNN top-5 =============================
        int p = bid & (P1 - 1);
        int b = bid >> LOGP1;

        float X[4], Y[4], Z[4];
#pragma unroll
        for (int s = 0; s < 4; ++s) {
            int v = tid + s * 256;
            if (v >= VV) v = VV - 1;
            const float* vp = verts + ((size_t)b * VV + v) * 3;
            X[s] = -2.0f * vp[0];
            Y[s] = -2.0f * vp[1];
            Z[s] = -2.0f * vp[2];
        }

        float t[4][KNN];
#pragma unroll
        for (int s = 0; s < 4; ++s)
#pragma unroll
            for (int k = 0; k < KNN; ++k) t[s][k] = INFINITY;

        const float* pb = obj_pts + ((size_t)b * OO + p * NPTS1) * 3;
        for (int c0 = 0; c0 < NPTS1; c0 += CH1) {
            for (int j = tid; j < CH1; j += 256) {
                const float* q = pb + (size_t)(c0 + j) * 3;
                float a0 = q[0], a1 = q[1], a2 = q[2];
                tile[j] = make_float4(a0, a1, a2, a0 * a0 + a1 * a1 + a2 * a2);
            }
            __syncthreads();
#pragma unroll 4
            for (int i = 0; i < CH1; ++i) {
                float4 q = tile[i];
#pragma unroll
                for (int s = 0; s < 4; ++s) {
                    float sv = fmaf(X[s], q.x, fmaf(Y[s], q.y, fmaf(Z[s], q.z, q.w)));
                    insert5_med3(t[s], sv);
                }
            }
            __syncthreads();
        }
        {
            size_t base = ((size_t)(b * P1 + p) * KNN) * VV;
#pragma unroll
            for (int s = 0; s < 4; ++s) {
                int v = tid + s * 256;
                if (v < VV) {
#pragma unroll
                    for (int k = 0; k < KNN; ++k)
                        top5[base + (size_t)k * VV + v] = t[s][k];
                }
            }
        }
        return;
    }

    // ================= Family 2: NN argmin (+ duties) ======================
    {
        int sub = bid - BB * P1;
        int p = sub & (P2 - 1);
        int b = sub >> LOGP2;

        bool wduty = (p == 0);                    // 16 blocks, one per b
        bool aduty = (p == 1 && b == 0);          // 1 block
        if (wduty || aduty) {
            if (tid < GG) {
                float x = init_anchors[tid * 3 + 0];
                float y = init_anchors[tid * 3 + 1];
                float z = init_anchors[tid * 3 + 2];
                anc[tid * 4 + 0] = x; anc[tid * 4 + 1] = y;
                anc[tid * 4 + 2] = z; anc[tid * 4 + 3] = x * x + y * y + z * z;
                smn[tid] = 0x7F800000u;
                smx[tid] = 0u;
                if (wduty) {
                    const float* cg2 = contact_gaussians + ((size_t)b * GG + tid) * 12;
                    const float* av = anchor_verts + ((size_t)b * GG + tid) * 3;
                    float c00 = cg2[3];
                    float c10 = cg2[6], c11 = cg2[7];
                    float c20 = cg2[9], c21 = cg2[10], c22 = cg2[11];
                    float L00 = sqrtf(c00);
                    float L10 = c10 / L00;
                    float L20 = c20 / L00;
                    float L11 = sqrtf(c11 - L10 * L10);
                    float L21 = (c21 - L20 * L10) / L11;
                    float L22 = sqrtf(c22 - L20 * L20 - L21 * L21);
                    float* c = cholb + tid * 10;
                    c[0] = L00; c[1] = L10; c[2] = L11;
                    c[3] = L20; c[4] = L21; c[5] = L22;
                    c[6] = logf(L00) + logf(L11) + logf(L22);
                    c[7] = cg2[0] + av[0];
                    c[8] = cg2[1] + av[1];
                    c[9] = cg2[2] + av[2];
                }
            }
            __syncthreads();
            for (int v = tid; v < VV; v += 256) {
                float x = init_verts[v * 3 + 0];
                float y = init_verts[v * 3 + 1];
                float z = init_verts[v * 3 + 2];
                float vv = x * x + y * y + z * z;
                float best = INFINITY;
                int bg = 0;
                for (int g = 0; g < GG; ++g) {
                    float d2 = vv + anc[g * 4 + 3] -
                               2.0f * (x * anc[g * 4 + 0] + y * anc[g * 4 + 1] + z * anc[g * 4 + 2]);
                    d2 = fmaxf(d2, 0.0f);
                    if (d2 < best) { best = d2; bg = g; }
                }
                gidl[v] = (unsigned short)bg;
                if (aduty) gid_ws[v] = bg;
            }
            __syncthreads();
            if (wduty) {
                for (int v = tid; v < VV; v += 256) {
                    int g = gidl[v];
                    const float* c = cholb + g * 10;
                    const float* vp = verts + ((size_t)b * VV + v) * 3;
                    float d0 = vp[0] - c[7];
                    float d1 = vp[1] - c[8];
                    float d2 = vp[2] - c[9];
                    float y0 = d0 / c[0];
                    float y1 = (d1 - c[1] * y0) / c[2];
                    float y2 = (d2 - c[3] * y0 - c[4] * y1) / c[5];
                    float maha = y0 * y0 + y1 * y1 + y2 * y2;
                    float wv = expf(-0.5f * (maha + THREE_LOG2PI) - c[6]);
                    w_ws[(size_t)b * VV + v] = wv;
                    unsigned int u = __float_as_uint(wv);
                    atomicMin(&smn[g], u);
                    atomicMax(&smx[g], u);
                }
                __syncthreads();
                if (tid < GG) {
                    segmn[b * GG + tid] = __uint_as_float(smn[tid]);
                    segmx[b * GG + tid] = __uint_as_float(smx[tid]);
                }
            }
            if (aduty) {
                if (tid < GG) {
                    int any = 0;
                    for (int bb = 0; bb < BB && !any; ++bb) {
                        for (int c = 0; c < 12; ++c) {
                            if (fabsf(contact_gaussians[((size_t)bb * GG + tid) * 12 + c]) > 1e-9f) {
                                any = 1;
                                break;
                            }
                        }
                    }
                    active_ws[tid] = any ? 1.0f : 0.0f;
                }
                if (tid == 0) { out[0] = 0.0f; out[1] = 0.0f; }
            }
            __syncthreads();
        }

        float X[4], Y[4], Z[4];
#pragma unroll
        for (int s = 0; s < 4; ++s) {
            int v = tid + s * 256;
            if (v >= VV) v = VV - 1;
            const float* vp = verts + ((size_t)b * VV + v) * 3;
            X[s] = -2.0f * vp[0];
            Y[s] = -2.0f * vp[1];
            Z[s] = -2.0f * vp[2];
        }

        float bs[4];
        int bi[4];
#pragma unroll
        for (int s = 0; s < 4; ++s) { bs[s] = INFINITY; bi[s] = 0; }

        const float* nbp = obj_normals + ((size_t)b * OO + p * NPTS2) * 6;
        for (int c0 = 0; c0 < NPTS2; c0 += CH2) {
            for (int j = tid; j < CH2; j += 256) {
                const float* r = nbp + (size_t)(c0 + j) * 6;
                float b0 = r[0], b1 = r[1], b2 = r[2];
                tile[j] = make_float4(b0, b1, b2, b0 * b0 + b1 * b1 + b2 * b2);
            }
            __syncthreads();
#pragma unroll 4
            for (int i = 0; i < CH2; ++i) {
                float4 n = tile[i];
                int gi = c0 + i;
#pragma unroll
                for (int s = 0; s < 4; ++s) {
                    float u = fmaf(X[s], n.x, fmaf(Y[s], n.y, fmaf(Z[s], n.z, n.w)));
                    if (u < bs[s]) { bs[s] = u; bi[s] = gi; }
                }
            }
            __syncthreads();
        }
#pragma unroll
        for (int s = 0; s < 4; ++s) {
            int v = tid + s * 256;
            if (v < VV) {
                unsigned long long key =
                    ((unsigned long long)fkey(bs[s]) << 32) |
                    (unsigned int)(p * NPTS2 + bi[s]);
                atomicMin(&amin[(size_t)b * VV + v], key);
            }
        }
    }
}

// ---------------- Kernel B: tree merge top5 + weights + reduce -------------
// grid = BB * 13 blocks of 256. tid = pi*64 + vi.
template <int LOGP1>
__global__ __launch_bounds__(256) void finalize_kernel(
    const float* __restrict__ top5,
    const unsigned long long* __restrict__ amin,
    const float* __restrict__ obj_normals,
    const float* __restrict__ verts,
    const int* __restrict__ gid,
    const float* __restrict__ w,
    const float* __restrict__ segmn,
    const float* __restrict__ segmx,
    const float* __restrict__ active,
    float* __restrict__ out) {
    constexpr int P1 = 1 << LOGP1;
    constexpr int NM1 = (P1 + 3) / 4;
    constexpr int NCH = (VV + 63) / 64;

    __shared__ float mt[4][KNN][64];
    __shared__ float rd[256], rp[256];

    int tid = threadIdx.x;
    int pi = tid >> 6;
    int vi = tid & 63;
    int b = blockIdx.x / NCH;
    int chunk = blockIdx.x - b * NCH;
    int v = chunk * 64 + vi;
    bool valid = v < VV;

    float m[KNN];
#pragma unroll
    for (int k = 0; k < KNN; ++k) m[k] = INFINITY;
    if (valid) {
#pragma unroll
        for (int r = 0; r < NM1; ++r) {
            int p = pi * NM1 + r;
            if (p < P1) {
                size_t base = ((size_t)(b * P1 + p) * KNN) * VV + v;
                float t[KNN];
#pragma unroll
                for (int k = 0; k < KNN; ++k) t[k] = top5[base + (size_t)k * VV];
                merge5_med3(m, t);
            }
        }
    }

#pragma unroll
    for (int k = 0; k < KNN; ++k) mt[pi][k][vi] = m[k];
    __syncthreads();

    if (pi < 2) {
        float t[KNN];
#pragma unroll
        for (int k = 0; k < KNN; ++k) t[k] = mt[pi + 2][k][vi];
        merge5_med3(m, t);
#pragma unroll
        for (int k = 0; k < KNN; ++k) mt[pi][k][vi] = m[k];
    }
    __syncthreads();

    float cd = 0.0f, cp = 0.0f;
    if (pi == 0 && valid) {
        float t[KNN];
#pragma unroll
        for (int k = 0; k < KNN; ++k) t[k] = mt[1][k][vi];
        merge5_med3(m, t);

        const float* vp = verts + ((size_t)b * VV + v) * 3;
        float vx = vp[0], vy = vp[1], vz = vp[2];
        float vv = vx * vx + vy * vy + vz * vz;

        int g = gid[v];
        float wv = w[(size_t)b * VV + v];
        float mn = segmn[b * GG + g];
        float mx = segmx[b * GG + g];
        float wn = (wv - mn) / (mx - mn);
        float eff = (active[g] != 0.0f && wn > 0.01f) ? wn : 0.0f;
        float sk = 0.0f;
#pragma unroll
        for (int k = 0; k < KNN; ++k) sk += sqrtf(fmaxf(vv + m[k], 0.0f));
        cd = eff * sk;

        int bi = (int)(unsigned int)(amin[(size_t)b * VV + v] & 0xFFFFFFFFull);
        const float* row = obj_normals + ((size_t)b * OO + bi) * 6;
        float n0 = row[3], n1 = row[4], n2 = row[5];
        float r0 = row[0] - 0.002f * n0;
        float r1 = row[1] - 0.002f * n1;
        float r2 = row[2] - 0.002f * n2;
        float dp = n0 * (vx - r0) + n1 * (vy - r1) + n2 * (vz - r2);
        cp = fmaxf(-dp, 0.0f);
    }

    rd[tid] = cd;
    rp[tid] = cp;
    __syncthreads();
    for (int s = 128; s > 0; s >>= 1) {
        if (tid < s) {
            rd[tid] += rd[tid + s];
            rp[tid] += rp[tid + s];
        }
        __syncthreads();
    }
    if (tid == 0) {
        atomicAdd(&out[0], rd[0] * (1.0f / ((float)BB * VV * KNN)));
        atomicAdd(&out[1], rp[0] * (1.0f / ((float)BB * VV)));
    }
}

template <int LOGP>
static void launch_all(const float* verts, const float* anchor_verts,
                       const float* obj_pts, const float* contact_gaussians,
                       const float* obj_normals, const float* init_verts,
                       const float* init_anchors, int* gid_ws, float* active_ws,
                       float* segmn, float* segmx, float* w_ws, float* top5,
                       unsigned long long* amin, float* out, hipStream_t stream) {
    constexpr int P = 1 << LOGP;
    constexpr int NCH = (VV + 63) / 64;
    dim3 block(256);
    hipLaunchKernelGGL((scan_kernel<LOGP, LOGP>), dim3(BB * 2 * P), block,
                       0, stream, verts, anchor_verts, obj_pts, contact_gaussians,
                       obj_normals, init_verts, init_anchors, gid_ws, active_ws,
                       segmn, segmx, w_ws, top5, amin, out);
    hipLaunchKernelGGL((finalize_kernel<LOGP>), dim3(BB * NCH), block, 0, stream,
                       top5, amin, obj_normals, verts, gid_ws, w_ws, segmn,
                       segmx, active_ws, out);
}

extern "C" void kernel_launch(void* const* d_in, const int* in_sizes, int n_in,
                              void* d_out, int out_size, void* d_ws, size_t ws_size,
                              hipStream_t stream) {
    const float* verts = (const float*)d_in[0];
    const float* anchor_verts = (const float*)d_in[1];
    const float* obj_pts = (const float*)d_in[2];
    const float* contact_gaussians = (const float*)d_in[3];
    const float* obj_normals = (const float*)d_in[4];
    const float* init_verts = (const float*)d_in[5];
    const float* init_anchors = (const float*)d_in[6];
    float* out = (float*)d_out;

    char* ws = (char*)d_ws;
    int* gid_ws = (int*)(ws + 0);                       // 778 ints -> 4096
    float* active_ws = (float*)(ws + 4096);             // 32 f     -> 4224
    float* segmn = (float*)(ws + 4224);                 // 512 f    -> 6272
    float* segmx = (float*)(ws + 6272);                 // 512 f    -> 8320
    float* w_ws = (float*)(ws + 8320);                  // 12448 f  -> 58112
    unsigned long long* amin = (unsigned long long*)(ws + 58112);  // B*V u64 -> 157696
    const size_t base = 157696;

    int logP = 5;
    while (logP > 0 &&
           base + (size_t)BB * (1 << logP) * KNN * VV * 4 > ws_size)
        --logP;

    float* top5 = (float*)(ws + base);

    // init packed argmin array to +inf pattern (capture-legal async memset)
    hipMemsetAsync(amin, 0xFF, (size_t)BB * VV * sizeof(unsigned long long),
                   stream);

#define LAUNCH(L)                                                              \
    launch_all<L>(verts, anchor_verts, obj_pts, contact_gaussians,             \
                  obj_normals, init_verts, init_anchors, gid_ws, active_ws,    \
                  segmn, segmx, w_ws, top5, amin, out, stream)
    switch (logP) {
        case 5: LAUNCH(5); break;
        case 4: LAUNCH(4); break;
        case 3: LAUNCH(3); break;
        case 2: LAUNCH(2); break;
        case 1: LAUNCH(1); break;
        default: LAUNCH(0); break;
    }
#undef LAUNCH
}